// Round 1
// baseline (2609.510 us; speedup 1.0000x reference)
//
#include <hip/hip_runtime.h>

#define DEV __device__ __forceinline__

typedef __attribute__((ext_vector_type(8))) short short8;
typedef __attribute__((ext_vector_type(4))) float f32x4;
typedef unsigned short u16;

constexpr int kV = 80000, kD = 300, kNN = 32, kEE = 64, kHH = 4, kCC = 75;
constexpr int kB = 32, kT = 35, kU = 1024, kVG = 50000;
constexpr int kG = kB * kT;          // 1120
constexpr int kM = kG;

constexpr size_t alignup(size_t x) { return (x + 255) & ~size_t(255); }
constexpr size_t OFF_BAR   = 0;
constexpr size_t OFF_WSRC  = 256;
constexpr size_t OFF_WDST  = alignup(OFF_WSRC + 1200 * 4);
constexpr size_t OFF_BIAS  = alignup(OFF_WDST + 1200 * 4);
constexpr size_t OFF_SIG   = alignup(OFF_BIAS + 3 * 4096 * 4);
constexpr size_t OFF_WCAT0 = alignup(OFF_SIG + (size_t)35 * 32 * 640 * 2);
constexpr size_t OFF_WCAT1 = alignup(OFF_WCAT0 + (size_t)4096 * 1664 * 2);
constexpr size_t OFF_WCAT2 = alignup(OFF_WCAT1 + (size_t)4096 * 2048 * 2);
constexpr size_t OFF_HIST  = alignup(OFF_WCAT2 + (size_t)4096 * 2048 * 2);
constexpr size_t OFF_CWS   = alignup(OFF_HIST + (size_t)3 * 35 * 32 * 1024 * 2);
constexpr size_t OFF_PART  = alignup(OFF_CWS + (size_t)3 * 32 * 1024 * 4);
constexpr size_t OFF_LSE   = alignup(OFF_PART + (size_t)1120 * 784 * 8);

DEV u16 f2bf(float f) {
  union { float f; unsigned u; } v; v.f = f;
  unsigned r = v.u + 0x7fffu + ((v.u >> 16) & 1u);
  return (u16)(r >> 16);
}
DEV float sigm(float x) { return 1.f / (1.f + expf(-x)); }
DEV f32x4 mfma16(short8 a, short8 b, f32x4 c) {
  return __builtin_amdgcn_mfma_f32_16x16x32_bf16(a, b, c, 0, 0, 0);
}

// ---------------- prep: ws_src/ws_dst (W @ att vectors), bias sums ----------
__global__ void prep_small(const float* __restrict__ gat_W,
                           const float* __restrict__ att_src,
                           const float* __restrict__ att_dst,
                           const float* __restrict__ b_ih,
                           const float* __restrict__ b_hh,
                           float* __restrict__ ws_src, float* __restrict__ ws_dst,
                           float* __restrict__ bias_sum) {
  int total = 1200 + 1200 + 3 * 4096;
  for (int i = blockIdx.x * blockDim.x + threadIdx.x; i < total; i += gridDim.x * blockDim.x) {
    if (i < 1200) {
      int d = i >> 2, h = i & 3;
      float s = 0.f;
      for (int c = 0; c < kCC; ++c) s += gat_W[d * 300 + h * kCC + c] * att_src[h * kCC + c];
      ws_src[i] = s;
    } else if (i < 2400) {
      int j = i - 1200; int d = j >> 2, h = j & 3;
      float s = 0.f;
      for (int c = 0; c < kCC; ++c) s += gat_W[d * 300 + h * kCC + c] * att_dst[h * kCC + c];
      ws_dst[j] = s;
    } else {
      int j = i - 2400;
      bias_sum[j] = b_ih[j] + b_hh[j];
    }
  }
}

// ---------------- prep: concatenated bf16 LSTM weights ----------------------
__global__ void wcat_prep(const float* __restrict__ W_ih0,
                          const float* __restrict__ W_ih_rest,
                          const float* __restrict__ W_hh,
                          u16* __restrict__ wcat0, u16* __restrict__ wcat1,
                          u16* __restrict__ wcat2) {
  const int n0 = 4096 * 1664;
  const int n12 = 4096 * 2048;
  int total = n0 + 2 * n12;
  for (int i = blockIdx.x * blockDim.x + threadIdx.x; i < total; i += gridDim.x * blockDim.x) {
    float v; u16* dst;
    if (i < n0) {
      int row = i / 1664, col = i - row * 1664;
      v = (col < 600) ? W_ih0[row * 600 + col]
        : (col < 640) ? 0.f
                      : W_hh[row * 1024 + (col - 640)];
      dst = wcat0 + i;
    } else {
      int j = i - n0; int l = j / n12; int k2 = j - l * n12;
      int row = k2 >> 11, col = k2 & 2047;
      v = (col < 1024) ? W_ih_rest[((size_t)l * 4096 + row) * 1024 + col]
                       : W_hh[((size_t)(l + 1) * 4096 + row) * 1024 + (col - 1024)];
      dst = (l == 0 ? wcat1 : wcat2) + k2;
    }
    *dst = f2bf(v);
  }
}

// ---------------- GAT (node-0 only, factored attention) ---------------------
__global__ void __launch_bounds__(256) gat_kernel(
    const int* __restrict__ x_indices, const int* __restrict__ edge_index,
    const float* __restrict__ X, const float* __restrict__ gat_W,
    const float* __restrict__ gat_bias, const float* __restrict__ ws_src,
    const float* __restrict__ ws_dst, u16* __restrict__ sig) {
  __shared__ float xs[32][301];
  __shared__ float a_s[32][4];
  __shared__ float a_d0[4];
  __shared__ float alpha[4][32];
  __shared__ float xw[4][301];
  __shared__ int allowed[32];
  int g = blockIdx.x, tid = threadIdx.x;
  const int* idx = x_indices + g * 32;
  for (int i = tid; i < 32 * 300; i += 256) {
    int j = i / 300, d2 = i - j * 300;
    xs[j][d2] = X[(size_t)idx[j] * 300 + d2];
  }
  if (tid < 32) allowed[tid] = (tid == 0) ? 1 : 0;
  __syncthreads();
  if (tid < 128) {
    int j = tid >> 2, h = tid & 3;
    float s = 0.f;
    for (int d2 = 0; d2 < 300; ++d2) s += xs[j][d2] * ws_src[d2 * 4 + h];
    a_s[j][h] = s;
  } else if (tid < 132) {
    int h = tid - 128; float s = 0.f;
    for (int d2 = 0; d2 < 300; ++d2) s += xs[0][d2] * ws_dst[d2 * 4 + h];
    a_d0[h] = s;
  } else if (tid >= 192) {
    int e = tid - 192;
    int src = edge_index[g * 128 + e];
    int dst = edge_index[g * 128 + 64 + e];
    if (dst == 0) allowed[src] = 1;
  }
  __syncthreads();
  if (tid < 4) {
    int h = tid;
    float ev[32];
    float mx = -1e30f;
    #pragma unroll
    for (int j = 0; j < 32; ++j) {
      float v = a_d0[h] + a_s[j][h];
      v = (v > 0.f) ? v : 0.2f * v;
      v = allowed[j] ? v : -1e9f;
      ev[j] = v; mx = fmaxf(mx, v);
    }
    float ssum = 0.f;
    #pragma unroll
    for (int j = 0; j < 32; ++j) { float p = expf(ev[j] - mx); ev[j] = p; ssum += p; }
    float inv = 1.f / ssum;
    #pragma unroll
    for (int j = 0; j < 32; ++j) alpha[h][j] = ev[j] * inv;
  }
  __syncthreads();
  for (int i = tid; i < 4 * 300; i += 256) {
    int h = i / 300, d2 = i - h * 300;
    float s = 0.f;
    #pragma unroll
    for (int j = 0; j < 32; ++j) s += alpha[h][j] * xs[j][d2];
    xw[h][d2] = s;
  }
  __syncthreads();
  int t = g % 35, b = g / 35;
  u16* srow = sig + ((size_t)t * 32 + b) * 640;
  for (int hc = tid; hc < 300; hc += 256) {
    srow[hc] = f2bf(xs[0][hc]);           // curr_emb = X[idx 0]
    int h = hc / 75;
    float s = gat_bias[hc];
    for (int d2 = 0; d2 < 300; ++d2) s += xw[h][d2] * gat_W[d2 * 300 + hc];
    srow[300 + hc] = f2bf(s);
  }
  for (int i2 = 600 + tid; i2 < 640; i2 += 256) srow[i2] = 0;  // zero pad
}

// ---------------- grid barrier (device-scope atomics) -----------------------
DEV void grid_barrier(unsigned* cnt, unsigned* gen, unsigned nb) {
  __syncthreads();
  if (threadIdx.x == 0) {
    __threadfence();
    unsigned g = __hip_atomic_load(gen, __ATOMIC_RELAXED, __HIP_MEMORY_SCOPE_AGENT);
    if (__hip_atomic_fetch_add(cnt, 1u, __ATOMIC_ACQ_REL, __HIP_MEMORY_SCOPE_AGENT) == nb - 1u) {
      __hip_atomic_store(cnt, 0u, __ATOMIC_RELAXED, __HIP_MEMORY_SCOPE_AGENT);
      __hip_atomic_fetch_add(gen, 1u, __ATOMIC_ACQ_REL, __HIP_MEMORY_SCOPE_AGENT);
    } else {
      while (__hip_atomic_load(gen, __ATOMIC_ACQUIRE, __HIP_MEMORY_SCOPE_AGENT) == g) {
        __builtin_amdgcn_s_sleep(4);
      }
    }
    __threadfence();
  }
  __syncthreads();
}

// ---------------- LSTM: 3 layers, wavefront (l,t), one persistent kernel ----
template <int KX>
DEV void lstm_run(const u16* __restrict__ xbase0, int xstride,
                  const u16* __restrict__ wc, const float* __restrict__ bias_sum,
                  u16* __restrict__ hist, float* __restrict__ c_ws,
                  unsigned* bar, int l, int u0, unsigned nb) {
  constexpr int KW = KX + 1024;
  const int tid = threadIdx.x;
  const int w = tid >> 6, lane = tid & 63, l15 = lane & 15, lhi = lane >> 4;
  __shared__ float gbuf[32][4][16];
  const u16* brow = wc + (size_t)(w * 1024 + u0 + l15) * KW + lhi * 8;
  u16* histL = hist + (size_t)l * 35 * 32 * 1024;
  float* crow = c_ws + (size_t)l * 32 * 1024 + u0;
  const float* bi = bias_sum + l * 4096 + u0;
  for (int s = 0; s < 37; ++s) {
    int t = s - l;
    if (t >= 0 && t < 35) {
      f32x4 acc0 = {0.f, 0.f, 0.f, 0.f}, acc1 = {0.f, 0.f, 0.f, 0.f};
      const u16* xrow = xbase0 + (size_t)t * 32 * xstride;
      const u16* a0p = xrow + l15 * xstride + lhi * 8;
      const u16* a1p = xrow + (l15 + 16) * xstride + lhi * 8;
      #pragma unroll 4
      for (int ks = 0; ks < KX / 32; ++ks) {
        int k = ks * 32;
        short8 bf = *(const short8*)(brow + k);
        short8 a0 = *(const short8*)(a0p + k);
        short8 a1 = *(const short8*)(a1p + k);
        acc0 = mfma16(a0, bf, acc0);
        acc1 = mfma16(a1, bf, acc1);
      }
      if (t > 0) {
        const u16* hrow = histL + (size_t)(t - 1) * 32 * 1024;
        const u16* brow2 = brow + KX;
        const u16* h0p = hrow + l15 * 1024 + lhi * 8;
        const u16* h1p = hrow + (l15 + 16) * 1024 + lhi * 8;
        #pragma unroll 4
        for (int ks = 0; ks < 32; ++ks) {
          int k = ks * 32;
          short8 bf = *(const short8*)(brow2 + k);
          short8 a0 = *(const short8*)(h0p + k);
          short8 a1 = *(const short8*)(h1p + k);
          acc0 = mfma16(a0, bf, acc0);
          acc1 = mfma16(a1, bf, acc1);
        }
      }
      #pragma unroll
      for (int r = 0; r < 4; ++r) {
        gbuf[lhi * 4 + r][w][l15] = acc0[r];
        gbuf[16 + lhi * 4 + r][w][l15] = acc1[r];
      }
      __syncthreads();
      #pragma unroll
      for (int p = 0; p < 2; ++p) {
        int pid = tid + p * 256;
        int b = pid >> 4, u = pid & 15;
        float iv = gbuf[b][0][u] + bi[u];
        float fv = gbuf[b][1][u] + bi[1024 + u];
        float gv = gbuf[b][2][u] + bi[2048 + u];
        float ov = gbuf[b][3][u] + bi[3072 + u];
        float cp = (t == 0) ? 0.f : crow[b * 1024 + u];
        float cc = sigm(fv) * cp + sigm(iv) * tanhf(gv);
        float hh = sigm(ov) * tanhf(cc);
        crow[b * 1024 + u] = cc;
        histL[((size_t)t * 32 + b) * 1024 + u0 + u] = f2bf(hh);
      }
      __syncthreads();
    }
    grid_barrier(bar, bar + 1, nb);
  }
}

__global__ void __launch_bounds__(256, 1) lstm_coop(
    const u16* __restrict__ sig, const u16* __restrict__ wcat0,
    const u16* __restrict__ wcat1, const u16* __restrict__ wcat2,
    const float* __restrict__ bias_sum, u16* __restrict__ hist,
    float* __restrict__ c_ws, unsigned* bar) {
  int l = blockIdx.x >> 6;
  int u0 = (blockIdx.x & 63) * 16;
  unsigned nb = gridDim.x;
  if (l == 0)      lstm_run<640>(sig, 640, wcat0, bias_sum, hist, c_ws, bar, 0, u0, nb);
  else if (l == 1) lstm_run<1024>(hist, 1024, wcat1, bias_sum, hist, c_ws, bar, 1, u0, nb);
  else             lstm_run<1024>(hist + (size_t)35 * 32 * 1024, 1024, wcat2, bias_sum, hist, c_ws, bar, 2, u0, nb);
}

// ---------------- logits GEMM (1120x50000x1024, bf16 MFMA) + row partials ---
__global__ void __launch_bounds__(256, 1) gemm_logits(
    const u16* __restrict__ hist2, const float* __restrict__ lin_W,
    const float* __restrict__ lin_b, float* __restrict__ out,
    float2* __restrict__ partials) {
  int bid = blockIdx.x;
  int bm = bid % 9, bn = bid / 9;
  int m0 = bm * 128, n0 = bn * 128;
  int tid = threadIdx.x, w = tid >> 6, lane = tid & 63, l15 = lane & 15, lhi = lane >> 4;
  int wm = w & 1, wn = w >> 1;
  __shared__ u16 As[128][48];
  __shared__ u16 Bs[128][48];
  f32x4 acc[4][4];
  #pragma unroll
  for (int i = 0; i < 4; ++i)
    #pragma unroll
    for (int j = 0; j < 4; ++j) { f32x4 z = {0.f, 0.f, 0.f, 0.f}; acc[i][j] = z; }

  for (int kt = 0; kt < 32; ++kt) {
    int k0 = kt * 32;
    #pragma unroll
    for (int q = 0; q < 2; ++q) {
      int c = tid * 2 + q; int row = c >> 2; int ch = c & 3;
      int m = m0 + row;
      uint4 av{0u, 0u, 0u, 0u};
      if (m < kM) {
        int b = m / 35; int t = m - b * 35;
        av = *(const uint4*)(hist2 + ((size_t)(t * 32 + b) << 10) + k0 + ch * 8);
      }
      *(uint4*)&As[row][ch * 8] = av;
      int n = n0 + row;
      uint4 bv{0u, 0u, 0u, 0u};
      if (n < kVG) {
        const float* src = lin_W + (size_t)n * 1024 + k0 + ch * 8;
        float4 f0 = *(const float4*)(src);
        float4 f1 = *(const float4*)(src + 4);
        bv.x = (unsigned)f2bf(f0.x) | ((unsigned)f2bf(f0.y) << 16);
        bv.y = (unsigned)f2bf(f0.z) | ((unsigned)f2bf(f0.w) << 16);
        bv.z = (unsigned)f2bf(f1.x) | ((unsigned)f2bf(f1.y) << 16);
        bv.w = (unsigned)f2bf(f1.z) | ((unsigned)f2bf(f1.w) << 16);
      }
      *(uint4*)&Bs[row][ch * 8] = bv;
    }
    __syncthreads();
    short8 bfr[4];
    #pragma unroll
    for (int nt = 0; nt < 4; ++nt)
      bfr[nt] = *(const short8*)&Bs[wn * 64 + nt * 16 + l15][lhi * 8];
    #pragma unroll
    for (int mt = 0; mt < 4; ++mt) {
      short8 af = *(const short8*)&As[wm * 64 + mt * 16 + l15][lhi * 8];
      #pragma unroll
      for (int nt = 0; nt < 4; ++nt)
        acc[mt][nt] = mfma16(af, bfr[nt], acc[mt][nt]);
    }
    __syncthreads();
  }
  // epilogue: store logits + per-(row, 64-col-group) max/sumexp partials
  float bcol[4]; int ncol[4];
  #pragma unroll
  for (int nt = 0; nt < 4; ++nt) {
    int n = n0 + wn * 64 + nt * 16 + l15;
    ncol[nt] = n;
    bcol[nt] = (n < kVG) ? lin_b[n] : -INFINITY;
  }
  #pragma unroll
  for (int mt = 0; mt < 4; ++mt) {
    #pragma unroll
    for (int r = 0; r < 4; ++r) {
      int m = m0 + wm * 64 + mt * 16 + lhi * 4 + r;
      float v0 = acc[mt][0][r] + bcol[0];
      float v1 = acc[mt][1][r] + bcol[1];
      float v2 = acc[mt][2][r] + bcol[2];
      float v3 = acc[mt][3][r] + bcol[3];
      bool mok = (m < kM);
      if (mok) {
        float* orow = out + (size_t)m * kVG;
        if (ncol[0] < kVG) orow[ncol[0]] = v0;
        if (ncol[1] < kVG) orow[ncol[1]] = v1;
        if (ncol[2] < kVG) orow[ncol[2]] = v2;
        if (ncol[3] < kVG) orow[ncol[3]] = v3;
      }
      float mx = fmaxf(fmaxf(v0, v1), fmaxf(v2, v3));
      #pragma unroll
      for (int d2 = 1; d2 < 16; d2 <<= 1) mx = fmaxf(mx, __shfl_xor(mx, d2, 64));
      float sv = 0.f;
      sv += (v0 > -1e30f) ? expf(v0 - mx) : 0.f;
      sv += (v1 > -1e30f) ? expf(v1 - mx) : 0.f;
      sv += (v2 > -1e30f) ? expf(v2 - mx) : 0.f;
      sv += (v3 > -1e30f) ? expf(v3 - mx) : 0.f;
      #pragma unroll
      for (int d2 = 1; d2 < 16; d2 <<= 1) sv += __shfl_xor(sv, d2, 64);
      if (mok && l15 == 0)
        partials[(size_t)m * 784 + bn * 2 + wn] = make_float2(mx, sv);
    }
  }
}

// ---------------- row logsumexp reduce --------------------------------------
__global__ void reduce_rows(const float2* __restrict__ partials, float* __restrict__ lse) {
  int m = blockIdx.x, tid = threadIdx.x;
  float mx = -INFINITY, s = 0.f;
  for (int j = tid; j < 782; j += 256) {
    float2 p = partials[(size_t)m * 784 + j];
    if (p.x > mx) { s = s * expf(mx - p.x) + p.y; mx = p.x; }
    else          { s += p.y * expf(p.x - mx); }
  }
  for (int d = 1; d < 64; d <<= 1) {
    float omx = __shfl_xor(mx, d, 64);
    float os  = __shfl_xor(s, d, 64);
    if (omx > mx) { s = s * expf(mx - omx) + os; mx = omx; }
    else          { s += os * expf(omx - mx); }
  }
  __shared__ float smx[4], ssum[4];
  int w = tid >> 6;
  if ((tid & 63) == 0) { smx[w] = mx; ssum[w] = s; }
  __syncthreads();
  if (tid == 0) {
    for (int i = 1; i < 4; ++i) {
      float omx = smx[i], os = ssum[i];
      if (omx > mx) { s = s * expf(mx - omx) + os; mx = omx; }
      else          { s += os * expf(omx - mx); }
    }
    lse[m] = mx + logf(s);
  }
}

// ---------------- in-place log_softmax subtract -----------------------------
__global__ void sub_lse(float* __restrict__ out, const float* __restrict__ lse) {
  const int total4 = 14000000;  // 1120*50000/4
  for (int i = blockIdx.x * blockDim.x + threadIdx.x; i < total4; i += gridDim.x * blockDim.x) {
    int m = i / 12500;
    float4 v = ((float4*)out)[i];
    float L = lse[m];
    v.x -= L; v.y -= L; v.z -= L; v.w -= L;
    ((float4*)out)[i] = v;
  }
}

// ---------------- launch ----------------------------------------------------
extern "C" void kernel_launch(void* const* d_in, const int* in_sizes, int n_in,
                              void* d_out, int out_size, void* d_ws, size_t ws_size,
                              hipStream_t stream) {
  const int*   x_indices  = (const int*)d_in[0];
  const int*   edge_index = (const int*)d_in[1];
  const float* X          = (const float*)d_in[2];
  const float* gat_W      = (const float*)d_in[3];
  const float* att_src    = (const float*)d_in[4];
  const float* att_dst    = (const float*)d_in[5];
  const float* gat_bias   = (const float*)d_in[6];
  const float* W_ih0      = (const float*)d_in[7];
  const float* W_ih_rest  = (const float*)d_in[8];
  const float* W_hh       = (const float*)d_in[9];
  const float* b_ih       = (const float*)d_in[10];
  const float* b_hh       = (const float*)d_in[11];
  const float* lin_W      = (const float*)d_in[12];
  const float* lin_b      = (const float*)d_in[13];
  float* out = (float*)d_out;
  char* ws = (char*)d_ws;

  unsigned* bar      = (unsigned*)(ws + OFF_BAR);
  float*    ws_src   = (float*)(ws + OFF_WSRC);
  float*    ws_dst   = (float*)(ws + OFF_WDST);
  float*    bias_sum = (float*)(ws + OFF_BIAS);
  u16*      sig      = (u16*)(ws + OFF_SIG);
  u16*      wcat0    = (u16*)(ws + OFF_WCAT0);
  u16*      wcat1    = (u16*)(ws + OFF_WCAT1);
  u16*      wcat2    = (u16*)(ws + OFF_WCAT2);
  u16*      hist     = (u16*)(ws + OFF_HIST);
  float*    c_ws     = (float*)(ws + OFF_CWS);
  float2*   partials = (float2*)(ws + OFF_PART);
  float*    lse      = (float*)(ws + OFF_LSE);

  hipMemsetAsync(ws + OFF_BAR, 0, 256, stream);
  prep_small<<<64, 256, 0, stream>>>(gat_W, att_src, att_dst, b_ih, b_hh,
                                     ws_src, ws_dst, bias_sum);
  wcat_prep<<<2048, 256, 0, stream>>>(W_ih0, W_ih_rest, W_hh, wcat0, wcat1, wcat2);
  gat_kernel<<<kG, 256, 0, stream>>>(x_indices, edge_index, X, gat_W, gat_bias,
                                     ws_src, ws_dst, sig);
  lstm_coop<<<192, 256, 0, stream>>>(sig, wcat0, wcat1, wcat2, bias_sum, hist, c_ws, bar);
  const u16* hist2 = hist + (size_t)2 * 35 * 32 * 1024;
  gemm_logits<<<9 * 391, 256, 0, stream>>>(hist2, lin_W, lin_b, out, partials);
  reduce_rows<<<kG, 256, 0, stream>>>(partials, lse);
  sub_lse<<<2048, 256, 0, stream>>>(out, lse);
}

// Round 2
// 2396.132 us; speedup vs baseline: 1.0891x; 1.0891x over previous
//
#include <hip/hip_runtime.h>

#define DEV __device__ __forceinline__

typedef __attribute__((ext_vector_type(8))) short short8;
typedef __attribute__((ext_vector_type(4))) float f32x4;
typedef unsigned short u16;

constexpr int kV = 80000, kD = 300, kNN = 32, kEE = 64, kHH = 4, kCC = 75;
constexpr int kB = 32, kT = 35, kU = 1024, kVG = 50000;
constexpr int kG = kB * kT;          // 1120
constexpr int kM = kG;

constexpr size_t alignup(size_t x) { return (x + 255) & ~size_t(255); }
constexpr size_t OFF_BAR   = 0;
constexpr size_t OFF_WSRC  = 256;
constexpr size_t OFF_WDST  = alignup(OFF_WSRC + 1200 * 4);
constexpr size_t OFF_BIAS  = alignup(OFF_WDST + 1200 * 4);
constexpr size_t OFF_SIG   = alignup(OFF_BIAS + 3 * 4096 * 4);
constexpr size_t OFF_WX0   = alignup(OFF_SIG + (size_t)35 * 32 * 640 * 2);
constexpr size_t OFF_WX12  = alignup(OFF_WX0 + (size_t)4096 * 640 * 2);
constexpr size_t OFF_GATES = alignup(OFF_WX12 + (size_t)2 * 4096 * 1024 * 2);
constexpr size_t OFF_HIST  = alignup(OFF_GATES + (size_t)1120 * 4096 * 4);
constexpr size_t OFF_PART  = alignup(OFF_HIST + (size_t)3 * 35 * 32 * 1024 * 2);
constexpr size_t OFF_LSE   = alignup(OFF_PART + (size_t)1120 * 784 * 8);

DEV u16 f2bf(float f) {
  union { float f; unsigned u; } v; v.f = f;
  unsigned r = v.u + 0x7fffu + ((v.u >> 16) & 1u);
  return (u16)(r >> 16);
}
DEV float sigm(float x) { return 1.f / (1.f + expf(-x)); }
DEV f32x4 mfma16(short8 a, short8 b, f32x4 c) {
  return __builtin_amdgcn_mfma_f32_16x16x32_bf16(a, b, c, 0, 0, 0);
}

// ---------------- prep: ws_src/ws_dst (W @ att vectors), bias sums ----------
__global__ void prep_small(const float* __restrict__ gat_W,
                           const float* __restrict__ att_src,
                           const float* __restrict__ att_dst,
                           const float* __restrict__ b_ih,
                           const float* __restrict__ b_hh,
                           float* __restrict__ ws_src, float* __restrict__ ws_dst,
                           float* __restrict__ bias_sum) {
  int total = 1200 + 1200 + 3 * 4096;
  for (int i = blockIdx.x * blockDim.x + threadIdx.x; i < total; i += gridDim.x * blockDim.x) {
    if (i < 1200) {
      int d = i >> 2, h = i & 3;
      float s = 0.f;
      for (int c = 0; c < kCC; ++c) s += gat_W[d * 300 + h * kCC + c] * att_src[h * kCC + c];
      ws_src[i] = s;
    } else if (i < 2400) {
      int j = i - 1200; int d = j >> 2, h = j & 3;
      float s = 0.f;
      for (int c = 0; c < kCC; ++c) s += gat_W[d * 300 + h * kCC + c] * att_dst[h * kCC + c];
      ws_dst[j] = s;
    } else {
      int j = i - 2400;
      bias_sum[j] = b_ih[j] + b_hh[j];
    }
  }
}

// ---------------- prep: bf16 input-transform weights ------------------------
__global__ void wx_prep(const float* __restrict__ W_ih0,
                        const float* __restrict__ W_ih_rest,
                        u16* __restrict__ wx0, u16* __restrict__ wx12) {
  const int n0 = 4096 * 640;
  const int n12 = 2 * 4096 * 1024;
  int total = n0 + n12;
  for (int i = blockIdx.x * blockDim.x + threadIdx.x; i < total; i += gridDim.x * blockDim.x) {
    if (i < n0) {
      int row = i / 640, col = i - row * 640;
      float v = (col < 600) ? W_ih0[row * 600 + col] : 0.f;
      wx0[i] = f2bf(v);
    } else {
      int j = i - n0;
      wx12[j] = f2bf(W_ih_rest[j]);
    }
  }
}

// ---------------- GAT (node-0 only, factored attention) ---------------------
__global__ void __launch_bounds__(256) gat_kernel(
    const int* __restrict__ x_indices, const int* __restrict__ edge_index,
    const float* __restrict__ X, const float* __restrict__ gat_W,
    const float* __restrict__ gat_bias, const float* __restrict__ ws_src,
    const float* __restrict__ ws_dst, u16* __restrict__ sig) {
  __shared__ float xs[32][301];
  __shared__ float a_s[32][4];
  __shared__ float a_d0[4];
  __shared__ float alpha[4][32];
  __shared__ float xw[4][301];
  __shared__ int allowed[32];
  int g = blockIdx.x, tid = threadIdx.x;
  const int* idx = x_indices + g * 32;
  for (int i = tid; i < 32 * 300; i += 256) {
    int j = i / 300, d2 = i - j * 300;
    xs[j][d2] = X[(size_t)idx[j] * 300 + d2];
  }
  if (tid < 32) allowed[tid] = (tid == 0) ? 1 : 0;
  __syncthreads();
  if (tid < 128) {
    int j = tid >> 2, h = tid & 3;
    float s = 0.f;
    for (int d2 = 0; d2 < 300; ++d2) s += xs[j][d2] * ws_src[d2 * 4 + h];
    a_s[j][h] = s;
  } else if (tid < 132) {
    int h = tid - 128; float s = 0.f;
    for (int d2 = 0; d2 < 300; ++d2) s += xs[0][d2] * ws_dst[d2 * 4 + h];
    a_d0[h] = s;
  } else if (tid >= 192) {
    int e = tid - 192;
    int src = edge_index[g * 128 + e];
    int dst = edge_index[g * 128 + 64 + e];
    if (dst == 0) allowed[src] = 1;
  }
  __syncthreads();
  if (tid < 4) {
    int h = tid;
    float ev[32];
    float mx = -1e30f;
    #pragma unroll
    for (int j = 0; j < 32; ++j) {
      float v = a_d0[h] + a_s[j][h];
      v = (v > 0.f) ? v : 0.2f * v;
      v = allowed[j] ? v : -1e9f;
      ev[j] = v; mx = fmaxf(mx, v);
    }
    float ssum = 0.f;
    #pragma unroll
    for (int j = 0; j < 32; ++j) { float p = expf(ev[j] - mx); ev[j] = p; ssum += p; }
    float inv = 1.f / ssum;
    #pragma unroll
    for (int j = 0; j < 32; ++j) alpha[h][j] = ev[j] * inv;
  }
  __syncthreads();
  for (int i = tid; i < 4 * 300; i += 256) {
    int h = i / 300, d2 = i - h * 300;
    float s = 0.f;
    #pragma unroll
    for (int j = 0; j < 32; ++j) s += alpha[h][j] * xs[j][d2];
    xw[h][d2] = s;
  }
  __syncthreads();
  int t = g % 35, b = g / 35;
  u16* srow = sig + ((size_t)t * 32 + b) * 640;
  for (int hc = tid; hc < 300; hc += 256) {
    srow[hc] = f2bf(xs[0][hc]);           // curr_emb = X[idx 0]
    int h = hc / 75;
    float s = gat_bias[hc];
    for (int d2 = 0; d2 < 300; ++d2) s += xw[h][d2] * gat_W[d2 * 300 + hc];
    srow[300 + hc] = f2bf(s);
  }
  for (int i2 = 600 + tid; i2 < 640; i2 += 256) srow[i2] = 0;  // zero pad
}

// ---------------- grid barrier (device-scope atomics) -----------------------
DEV void grid_barrier(unsigned* cnt, unsigned* gen, unsigned nb) {
  __syncthreads();
  if (threadIdx.x == 0) {
    __threadfence();
    unsigned g = __hip_atomic_load(gen, __ATOMIC_RELAXED, __HIP_MEMORY_SCOPE_AGENT);
    if (__hip_atomic_fetch_add(cnt, 1u, __ATOMIC_ACQ_REL, __HIP_MEMORY_SCOPE_AGENT) == nb - 1u) {
      __hip_atomic_store(cnt, 0u, __ATOMIC_RELAXED, __HIP_MEMORY_SCOPE_AGENT);
      __hip_atomic_fetch_add(gen, 1u, __ATOMIC_ACQ_REL, __HIP_MEMORY_SCOPE_AGENT);
    } else {
      while (__hip_atomic_load(gen, __ATOMIC_ACQUIRE, __HIP_MEMORY_SCOPE_AGENT) == g) {
        __builtin_amdgcn_s_sleep(4);
      }
    }
    __threadfence();
  }
  __syncthreads();
}

// ---------------- bulk input-gate GEMM: gates[m][4096] = A[m][K] @ Bw[4096][K]^T
__global__ void __launch_bounds__(256, 1) gemm_ig(
    const u16* __restrict__ A, const u16* __restrict__ Bw,
    float* __restrict__ gates, int K) {
  int bid = blockIdx.x;
  int bm = bid % 9, bn = bid / 9;
  int m0 = bm * 128, n0 = bn * 128;
  int tid = threadIdx.x, w = tid >> 6, lane = tid & 63, l15 = lane & 15, lhi = lane >> 4;
  int wm = w & 1, wn = w >> 1;
  __shared__ u16 As[128][40];
  __shared__ u16 Bs[128][40];
  f32x4 acc[4][4];
  #pragma unroll
  for (int i = 0; i < 4; ++i)
    #pragma unroll
    for (int j = 0; j < 4; ++j) { f32x4 z = {0.f, 0.f, 0.f, 0.f}; acc[i][j] = z; }

  int nkt = K >> 5;
  for (int kt = 0; kt < nkt; ++kt) {
    int k0 = kt * 32;
    #pragma unroll
    for (int q = 0; q < 2; ++q) {
      int c = tid * 2 + q; int row = c >> 2; int ch = c & 3;
      int m = m0 + row;
      uint4 av{0u, 0u, 0u, 0u};
      if (m < kM) av = *(const uint4*)(A + (size_t)m * K + k0 + ch * 8);
      *(uint4*)&As[row][ch * 8] = av;
      int n = n0 + row;
      uint4 bv = *(const uint4*)(Bw + (size_t)n * K + k0 + ch * 8);
      *(uint4*)&Bs[row][ch * 8] = bv;
    }
    __syncthreads();
    short8 bfr[4];
    #pragma unroll
    for (int nt = 0; nt < 4; ++nt)
      bfr[nt] = *(const short8*)&Bs[wn * 64 + nt * 16 + l15][lhi * 8];
    #pragma unroll
    for (int mt = 0; mt < 4; ++mt) {
      short8 af = *(const short8*)&As[wm * 64 + mt * 16 + l15][lhi * 8];
      #pragma unroll
      for (int nt = 0; nt < 4; ++nt)
        acc[mt][nt] = mfma16(af, bfr[nt], acc[mt][nt]);
    }
    __syncthreads();
  }
  #pragma unroll
  for (int mt = 0; mt < 4; ++mt) {
    #pragma unroll
    for (int r = 0; r < 4; ++r) {
      int m = m0 + wm * 64 + mt * 16 + lhi * 4 + r;
      if (m < kM) {
        float* orow = gates + (size_t)m * 4096;
        #pragma unroll
        for (int nt = 0; nt < 4; ++nt) {
          int n = n0 + wn * 64 + nt * 16 + l15;
          orow[n] = acc[mt][nt][r];
        }
      }
    }
  }
}

// ---------------- LSTM recurrence: one layer, W_hh LDS-resident -------------
// 128 blocks, block p owns units [8p, 8p+8). 34 grid barriers.
__global__ void __launch_bounds__(256, 1) lstm_rec(
    const float* __restrict__ W_hh_l,   // [4096][1024] fp32, this layer
    const float* __restrict__ gates,    // [1120][4096] f32 (x-part, precomputed)
    const float* __restrict__ bias_l,   // [4096]
    u16* __restrict__ hout,             // [35*32][1024] bf16
    unsigned* bar) {
  const int p = blockIdx.x;
  const int tid = threadIdx.x;
  const int w = tid >> 6, lane = tid & 63, l15 = lane & 15, lhi = lane >> 4;
  __shared__ u16 whs[32][1032];         // rows: idx = g*8+jj -> global g*1024+8p+jj
  __shared__ float pred[4][32][33];     // [wave][w-row][batch]
  for (int i = tid; i < 32 * 256; i += 256) {
    int row = i >> 8, seg = i & 255;
    int g = row >> 3, jj = row & 7;
    const float* src = W_hh_l + ((size_t)(g * 1024 + p * 8 + jj)) * 1024 + seg * 4;
    float4 f = *(const float4*)src;
    u16 tmp[4] = {f2bf(f.x), f2bf(f.y), f2bf(f.z), f2bf(f.w)};
    *(uint2*)&whs[row][seg * 4] = *(const uint2*)tmp;
  }
  const int b = tid >> 3, jj = tid & 7;
  float bias_r[4];
  #pragma unroll
  for (int g = 0; g < 4; ++g) bias_r[g] = bias_l[g * 1024 + p * 8 + jj];
  float c_reg = 0.f;
  const int kbase = w * 256;

  for (int t = 0; t < 35; ++t) {
    float gx[4];
    const float* gp = gates + ((size_t)(t * 32 + b)) * 4096 + p * 8 + jj;
    #pragma unroll
    for (int g = 0; g < 4; ++g) gx[g] = gp[g * 1024];
    if (t > 0) {
      const u16* hp = hout + (size_t)(t - 1) * 32 * 1024;
      const u16* hrow0 = hp + l15 * 1024 + lhi * 8;
      const u16* hrow1 = hp + (l15 + 16) * 1024 + lhi * 8;
      f32x4 acc00 = {0,0,0,0}, acc01 = {0,0,0,0}, acc10 = {0,0,0,0}, acc11 = {0,0,0,0};
      #pragma unroll
      for (int kk = 0; kk < 8; ++kk) {
        int k = kbase + kk * 32;
        short8 bf0 = *(const short8*)(hrow0 + k);
        short8 bf1 = *(const short8*)(hrow1 + k);
        short8 af0 = *(const short8*)&whs[l15][k + lhi * 8];
        short8 af1 = *(const short8*)&whs[16 + l15][k + lhi * 8];
        acc00 = mfma16(af0, bf0, acc00);
        acc01 = mfma16(af0, bf1, acc01);
        acc10 = mfma16(af1, bf0, acc10);
        acc11 = mfma16(af1, bf1, acc11);
      }
      #pragma unroll
      for (int r = 0; r < 4; ++r) {
        pred[w][lhi * 4 + r][l15]       = acc00[r];
        pred[w][lhi * 4 + r][l15 + 16]  = acc01[r];
        pred[w][16 + lhi * 4 + r][l15]      = acc10[r];
        pred[w][16 + lhi * 4 + r][l15 + 16] = acc11[r];
      }
      __syncthreads();
    }
    float pre[4];
    #pragma unroll
    for (int g = 0; g < 4; ++g) {
      float s = 0.f;
      if (t > 0) {
        int row = g * 8 + jj;
        s = pred[0][row][b] + pred[1][row][b] + pred[2][row][b] + pred[3][row][b];
      }
      pre[g] = s;
    }
    float iv = gx[0] + pre[0] + bias_r[0];
    float fv = gx[1] + pre[1] + bias_r[1];
    float gv = gx[2] + pre[2] + bias_r[2];
    float ov = gx[3] + pre[3] + bias_r[3];
    float cc = sigm(fv) * c_reg + sigm(iv) * tanhf(gv);
    float hh = sigm(ov) * tanhf(cc);
    c_reg = cc;
    hout[((size_t)(t * 32 + b)) * 1024 + p * 8 + jj] = f2bf(hh);
    if (t < 34) grid_barrier(bar, bar + 1, 128u);
  }
}

// ---------------- logits GEMM (1120x50000x1024, bf16 MFMA) + row partials ---
__global__ void __launch_bounds__(256, 1) gemm_logits(
    const u16* __restrict__ hist2, const float* __restrict__ lin_W,
    const float* __restrict__ lin_b, float* __restrict__ out,
    float2* __restrict__ partials) {
  int bid = blockIdx.x;
  int bm = bid % 9, bn = bid / 9;
  int m0 = bm * 128, n0 = bn * 128;
  int tid = threadIdx.x, w = tid >> 6, lane = tid & 63, l15 = lane & 15, lhi = lane >> 4;
  int wm = w & 1, wn = w >> 1;
  __shared__ u16 As[128][48];
  __shared__ u16 Bs[128][48];
  f32x4 acc[4][4];
  #pragma unroll
  for (int i = 0; i < 4; ++i)
    #pragma unroll
    for (int j = 0; j < 4; ++j) { f32x4 z = {0.f, 0.f, 0.f, 0.f}; acc[i][j] = z; }

  for (int kt = 0; kt < 32; ++kt) {
    int k0 = kt * 32;
    #pragma unroll
    for (int q = 0; q < 2; ++q) {
      int c = tid * 2 + q; int row = c >> 2; int ch = c & 3;
      int m = m0 + row;
      uint4 av{0u, 0u, 0u, 0u};
      if (m < kM) {
        int b = m / 35; int t = m - b * 35;
        av = *(const uint4*)(hist2 + ((size_t)(t * 32 + b) << 10) + k0 + ch * 8);
      }
      *(uint4*)&As[row][ch * 8] = av;
      int n = n0 + row;
      uint4 bv{0u, 0u, 0u, 0u};
      if (n < kVG) {
        const float* src = lin_W + (size_t)n * 1024 + k0 + ch * 8;
        float4 f0 = *(const float4*)(src);
        float4 f1 = *(const float4*)(src + 4);
        bv.x = (unsigned)f2bf(f0.x) | ((unsigned)f2bf(f0.y) << 16);
        bv.y = (unsigned)f2bf(f0.z) | ((unsigned)f2bf(f0.w) << 16);
        bv.z = (unsigned)f2bf(f1.x) | ((unsigned)f2bf(f1.y) << 16);
        bv.w = (unsigned)f2bf(f1.z) | ((unsigned)f2bf(f1.w) << 16);
      }
      *(uint4*)&Bs[row][ch * 8] = bv;
    }
    __syncthreads();
    short8 bfr[4];
    #pragma unroll
    for (int nt = 0; nt < 4; ++nt)
      bfr[nt] = *(const short8*)&Bs[wn * 64 + nt * 16 + l15][lhi * 8];
    #pragma unroll
    for (int mt = 0; mt < 4; ++mt) {
      short8 af = *(const short8*)&As[wm * 64 + mt * 16 + l15][lhi * 8];
      #pragma unroll
      for (int nt = 0; nt < 4; ++nt)
        acc[mt][nt] = mfma16(af, bfr[nt], acc[mt][nt]);
    }
    __syncthreads();
  }
  // epilogue: store logits + per-(row, 64-col-group) max/sumexp partials
  float bcol[4]; int ncol[4];
  #pragma unroll
  for (int nt = 0; nt < 4; ++nt) {
    int n = n0 + wn * 64 + nt * 16 + l15;
    ncol[nt] = n;
    bcol[nt] = (n < kVG) ? lin_b[n] : -INFINITY;
  }
  #pragma unroll
  for (int mt = 0; mt < 4; ++mt) {
    #pragma unroll
    for (int r = 0; r < 4; ++r) {
      int m = m0 + wm * 64 + mt * 16 + lhi * 4 + r;
      float v0 = acc[mt][0][r] + bcol[0];
      float v1 = acc[mt][1][r] + bcol[1];
      float v2 = acc[mt][2][r] + bcol[2];
      float v3 = acc[mt][3][r] + bcol[3];
      bool mok = (m < kM);
      if (mok) {
        float* orow = out + (size_t)m * kVG;
        if (ncol[0] < kVG) orow[ncol[0]] = v0;
        if (ncol[1] < kVG) orow[ncol[1]] = v1;
        if (ncol[2] < kVG) orow[ncol[2]] = v2;
        if (ncol[3] < kVG) orow[ncol[3]] = v3;
      }
      float mx = fmaxf(fmaxf(v0, v1), fmaxf(v2, v3));
      #pragma unroll
      for (int d2 = 1; d2 < 16; d2 <<= 1) mx = fmaxf(mx, __shfl_xor(mx, d2, 64));
      float sv = 0.f;
      sv += (v0 > -1e30f) ? expf(v0 - mx) : 0.f;
      sv += (v1 > -1e30f) ? expf(v1 - mx) : 0.f;
      sv += (v2 > -1e30f) ? expf(v2 - mx) : 0.f;
      sv += (v3 > -1e30f) ? expf(v3 - mx) : 0.f;
      #pragma unroll
      for (int d2 = 1; d2 < 16; d2 <<= 1) sv += __shfl_xor(sv, d2, 64);
      if (mok && l15 == 0)
        partials[(size_t)m * 784 + bn * 2 + wn] = make_float2(mx, sv);
    }
  }
}

// ---------------- row logsumexp reduce --------------------------------------
__global__ void reduce_rows(const float2* __restrict__ partials, float* __restrict__ lse) {
  int m = blockIdx.x, tid = threadIdx.x;
  float mx = -INFINITY, s = 0.f;
  for (int j = tid; j < 782; j += 256) {
    float2 p = partials[(size_t)m * 784 + j];
    if (p.x > mx) { s = s * expf(mx - p.x) + p.y; mx = p.x; }
    else          { s += p.y * expf(p.x - mx); }
  }
  for (int d = 1; d < 64; d <<= 1) {
    float omx = __shfl_xor(mx, d, 64);
    float os  = __shfl_xor(s, d, 64);
    if (omx > mx) { s = s * expf(mx - omx) + os; mx = omx; }
    else          { s += os * expf(omx - mx); }
  }
  __shared__ float smx[4], ssum[4];
  int w = tid >> 6;
  if ((tid & 63) == 0) { smx[w] = mx; ssum[w] = s; }
  __syncthreads();
  if (tid == 0) {
    for (int i = 1; i < 4; ++i) {
      float omx = smx[i], os = ssum[i];
      if (omx > mx) { s = s * expf(mx - omx) + os; mx = omx; }
      else          { s += os * expf(omx - mx); }
    }
    lse[m] = mx + logf(s);
  }
}

// ---------------- in-place log_softmax subtract -----------------------------
__global__ void sub_lse(float* __restrict__ out, const float* __restrict__ lse) {
  const int total4 = 14000000;  // 1120*50000/4
  for (int i = blockIdx.x * blockDim.x + threadIdx.x; i < total4; i += gridDim.x * blockDim.x) {
    int m = i / 12500;
    float4 v = ((float4*)out)[i];
    float L = lse[m];
    v.x -= L; v.y -= L; v.z -= L; v.w -= L;
    ((float4*)out)[i] = v;
  }
}

// ---------------- launch ----------------------------------------------------
extern "C" void kernel_launch(void* const* d_in, const int* in_sizes, int n_in,
                              void* d_out, int out_size, void* d_ws, size_t ws_size,
                              hipStream_t stream) {
  const int*   x_indices  = (const int*)d_in[0];
  const int*   edge_index = (const int*)d_in[1];
  const float* X          = (const float*)d_in[2];
  const float* gat_W      = (const float*)d_in[3];
  const float* att_src    = (const float*)d_in[4];
  const float* att_dst    = (const float*)d_in[5];
  const float* gat_bias   = (const float*)d_in[6];
  const float* W_ih0      = (const float*)d_in[7];
  const float* W_ih_rest  = (const float*)d_in[8];
  const float* W_hh       = (const float*)d_in[9];
  const float* b_ih       = (const float*)d_in[10];
  const float* b_hh       = (const float*)d_in[11];
  const float* lin_W      = (const float*)d_in[12];
  const float* lin_b      = (const float*)d_in[13];
  float* out = (float*)d_out;
  char* ws = (char*)d_ws;

  unsigned* bar      = (unsigned*)(ws + OFF_BAR);
  float*    ws_src   = (float*)(ws + OFF_WSRC);
  float*    ws_dst   = (float*)(ws + OFF_WDST);
  float*    bias_sum = (float*)(ws + OFF_BIAS);
  u16*      sig      = (u16*)(ws + OFF_SIG);
  u16*      wx0      = (u16*)(ws + OFF_WX0);
  u16*      wx12     = (u16*)(ws + OFF_WX12);
  float*    gates    = (float*)(ws + OFF_GATES);
  u16*      hist     = (u16*)(ws + OFF_HIST);
  float2*   partials = (float2*)(ws + OFF_PART);
  float*    lse      = (float*)(ws + OFF_LSE);

  u16* hist0 = hist;
  u16* hist1 = hist + (size_t)35 * 32 * 1024;
  u16* hist2 = hist + (size_t)2 * 35 * 32 * 1024;

  hipMemsetAsync(ws + OFF_BAR, 0, 256, stream);
  prep_small<<<64, 256, 0, stream>>>(gat_W, att_src, att_dst, b_ih, b_hh,
                                     ws_src, ws_dst, bias_sum);
  wx_prep<<<1024, 256, 0, stream>>>(W_ih0, W_ih_rest, wx0, wx12);
  gat_kernel<<<kG, 256, 0, stream>>>(x_indices, edge_index, X, gat_W, gat_bias,
                                     ws_src, ws_dst, sig);
  // layer 0
  gemm_ig<<<288, 256, 0, stream>>>(sig, wx0, gates, 640);
  lstm_rec<<<128, 256, 0, stream>>>(W_hh, gates, bias_sum, hist0, bar);
  // layer 1
  gemm_ig<<<288, 256, 0, stream>>>(hist0, wx12, gates, 1024);
  lstm_rec<<<128, 256, 0, stream>>>(W_hh + (size_t)4096 * 1024, gates,
                                    bias_sum + 4096, hist1, bar);
  // layer 2
  gemm_ig<<<288, 256, 0, stream>>>(hist1, wx12 + (size_t)4096 * 1024, gates, 1024);
  lstm_rec<<<128, 256, 0, stream>>>(W_hh + (size_t)2 * 4096 * 1024, gates,
                                    bias_sum + 8192, hist2, bar);
  // logits + log_softmax
  gemm_logits<<<9 * 391, 256, 0, stream>>>(hist2, lin_W, lin_b, out, partials);
  reduce_rows<<<kG, 256, 0, stream>>>(partials, lse);
  sub_lse<<<2048, 256, 0, stream>>>(out, lse);
}

// Round 3
// 1875.172 us; speedup vs baseline: 1.3916x; 1.2778x over previous
//
#include <hip/hip_runtime.h>

#define DEV __device__ __forceinline__

typedef __attribute__((ext_vector_type(8))) short short8;
typedef __attribute__((ext_vector_type(4))) float f32x4;
typedef unsigned short u16;

constexpr int kV = 80000, kD = 300, kNN = 32, kEE = 64, kHH = 4, kCC = 75;
constexpr int kB = 32, kT = 35, kU = 1024, kVG = 50000;
constexpr int kG = kB * kT;          // 1120
constexpr int kM = kG;

constexpr size_t alignup(size_t x) { return (x + 255) & ~size_t(255); }
constexpr size_t OFF_BAR   = 0;
constexpr size_t OFF_WSRC  = 256;
constexpr size_t OFF_WDST  = alignup(OFF_WSRC + 1200 * 4);
constexpr size_t OFF_BIAS  = alignup(OFF_WDST + 1200 * 4);
constexpr size_t OFF_SIG   = alignup(OFF_BIAS + 3 * 4096 * 4);
constexpr size_t OFF_WX0   = alignup(OFF_SIG + (size_t)35 * 32 * 640 * 2);
constexpr size_t OFF_WX12  = alignup(OFF_WX0 + (size_t)4096 * 640 * 2);
constexpr size_t OFF_GATES = alignup(OFF_WX12 + (size_t)2 * 4096 * 1024 * 2);
constexpr size_t OFF_HIST  = alignup(OFF_GATES + (size_t)1120 * 4096 * 4);
constexpr size_t OFF_PART  = alignup(OFF_HIST + (size_t)3 * 35 * 32 * 1024 * 2);
constexpr size_t OFF_LSE   = alignup(OFF_PART + (size_t)1120 * 784 * 8);
constexpr size_t OFF_LINWB = alignup(OFF_LSE + 1120 * 4);
constexpr size_t kLinWBytes = (size_t)kVG * 1024 * 2;
constexpr size_t kNeedBW   = OFF_LINWB + kLinWBytes;

DEV u16 f2bf(float f) {
  union { float f; unsigned u; } v; v.f = f;
  unsigned r = v.u + 0x7fffu + ((v.u >> 16) & 1u);
  return (u16)(r >> 16);
}
// fast transcendentals via v_exp_f32 (2^x) + v_rcp_f32; abs tolerance is ~0.2
DEV float fexp(float x) { return __builtin_amdgcn_exp2f(x * 1.4426950408889634f); }
DEV float fsigm(float x) {
  float t = __builtin_amdgcn_exp2f(-1.4426950408889634f * x);
  return __builtin_amdgcn_rcpf(1.f + t);
}
DEV float ftanh(float x) {
  float xc = fminf(fmaxf(x, -20.f), 20.f);
  float t = __builtin_amdgcn_exp2f(2.8853900817779268f * xc);
  return (t - 1.f) * __builtin_amdgcn_rcpf(t + 1.f);
}
DEV f32x4 mfma16(short8 a, short8 b, f32x4 c) {
  return __builtin_amdgcn_mfma_f32_16x16x32_bf16(a, b, c, 0, 0, 0);
}

// ---------------- prep: ws_src/ws_dst (W @ att vectors), bias sums ----------
__global__ void prep_small(const float* __restrict__ gat_W,
                           const float* __restrict__ att_src,
                           const float* __restrict__ att_dst,
                           const float* __restrict__ b_ih,
                           const float* __restrict__ b_hh,
                           float* __restrict__ ws_src, float* __restrict__ ws_dst,
                           float* __restrict__ bias_sum) {
  int total = 1200 + 1200 + 3 * 4096;
  for (int i = blockIdx.x * blockDim.x + threadIdx.x; i < total; i += gridDim.x * blockDim.x) {
    if (i < 1200) {
      int d = i >> 2, h = i & 3;
      float s = 0.f;
      for (int c = 0; c < kCC; ++c) s += gat_W[d * 300 + h * kCC + c] * att_src[h * kCC + c];
      ws_src[i] = s;
    } else if (i < 2400) {
      int j = i - 1200; int d = j >> 2, h = j & 3;
      float s = 0.f;
      for (int c = 0; c < kCC; ++c) s += gat_W[d * 300 + h * kCC + c] * att_dst[h * kCC + c];
      ws_dst[j] = s;
    } else {
      int j = i - 2400;
      bias_sum[j] = b_ih[j] + b_hh[j];
    }
  }
}

// ---------------- prep: bf16 input-transform weights ------------------------
__global__ void wx_prep(const float* __restrict__ W_ih0,
                        const float* __restrict__ W_ih_rest,
                        u16* __restrict__ wx0, u16* __restrict__ wx12) {
  const int n0 = 4096 * 640;
  const int n12 = 2 * 4096 * 1024;
  int total = n0 + n12;
  for (int i = blockIdx.x * blockDim.x + threadIdx.x; i < total; i += gridDim.x * blockDim.x) {
    if (i < n0) {
      int row = i / 640, col = i - row * 640;
      float v = (col < 600) ? W_ih0[row * 600 + col] : 0.f;
      wx0[i] = f2bf(v);
    } else {
      int j = i - n0;
      wx12[j] = f2bf(W_ih_rest[j]);
    }
  }
}

// ---------------- prep: bf16 copy of lin_W (halves GEMM B traffic) ----------
__global__ void wb_conv(const float* __restrict__ W, u16* __restrict__ Wb) {
  const long n = (long)kVG * 1024;
  long stride = (long)gridDim.x * blockDim.x * 8;
  for (long i = (long)(blockIdx.x * blockDim.x + threadIdx.x) * 8; i < n; i += stride) {
    float4 a = *(const float4*)(W + i);
    float4 b = *(const float4*)(W + i + 4);
    u16 t[8] = {f2bf(a.x), f2bf(a.y), f2bf(a.z), f2bf(a.w),
                f2bf(b.x), f2bf(b.y), f2bf(b.z), f2bf(b.w)};
    *(uint4*)(Wb + i) = *(const uint4*)t;
  }
}

// ---------------- GAT (node-0 only, factored attention) ---------------------
__global__ void __launch_bounds__(256) gat_kernel(
    const int* __restrict__ x_indices, const int* __restrict__ edge_index,
    const float* __restrict__ X, const float* __restrict__ gat_W,
    const float* __restrict__ gat_bias, const float* __restrict__ ws_src,
    const float* __restrict__ ws_dst, u16* __restrict__ sig) {
  __shared__ float xs[32][301];
  __shared__ float a_s[32][4];
  __shared__ float a_d0[4];
  __shared__ float alpha[4][32];
  __shared__ float xw[4][301];
  __shared__ int allowed[32];
  int g = blockIdx.x, tid = threadIdx.x;
  const int* idx = x_indices + g * 32;
  for (int i = tid; i < 32 * 300; i += 256) {
    int j = i / 300, d2 = i - j * 300;
    xs[j][d2] = X[(size_t)idx[j] * 300 + d2];
  }
  if (tid < 32) allowed[tid] = (tid == 0) ? 1 : 0;
  __syncthreads();
  if (tid < 128) {
    int j = tid >> 2, h = tid & 3;
    float s = 0.f;
    for (int d2 = 0; d2 < 300; ++d2) s += xs[j][d2] * ws_src[d2 * 4 + h];
    a_s[j][h] = s;
  } else if (tid < 132) {
    int h = tid - 128; float s = 0.f;
    for (int d2 = 0; d2 < 300; ++d2) s += xs[0][d2] * ws_dst[d2 * 4 + h];
    a_d0[h] = s;
  } else if (tid >= 192) {
    int e = tid - 192;
    int src = edge_index[g * 128 + e];
    int dst = edge_index[g * 128 + 64 + e];
    if (dst == 0) allowed[src] = 1;
  }
  __syncthreads();
  if (tid < 4) {
    int h = tid;
    float ev[32];
    float mx = -1e30f;
    #pragma unroll
    for (int j = 0; j < 32; ++j) {
      float v = a_d0[h] + a_s[j][h];
      v = (v > 0.f) ? v : 0.2f * v;
      v = allowed[j] ? v : -1e9f;
      ev[j] = v; mx = fmaxf(mx, v);
    }
    float ssum = 0.f;
    #pragma unroll
    for (int j = 0; j < 32; ++j) { float p = fexp(ev[j] - mx); ev[j] = p; ssum += p; }
    float inv = 1.f / ssum;
    #pragma unroll
    for (int j = 0; j < 32; ++j) alpha[h][j] = ev[j] * inv;
  }
  __syncthreads();
  for (int i = tid; i < 4 * 300; i += 256) {
    int h = i / 300, d2 = i - h * 300;
    float s = 0.f;
    #pragma unroll
    for (int j = 0; j < 32; ++j) s += alpha[h][j] * xs[j][d2];
    xw[h][d2] = s;
  }
  __syncthreads();
  int t = g % 35, b = g / 35;
  u16* srow = sig + ((size_t)t * 32 + b) * 640;
  for (int hc = tid; hc < 300; hc += 256) {
    srow[hc] = f2bf(xs[0][hc]);           // curr_emb = X[idx 0]
    int h = hc / 75;
    float s = gat_bias[hc];
    for (int d2 = 0; d2 < 300; ++d2) s += xw[h][d2] * gat_W[d2 * 300 + hc];
    srow[300 + hc] = f2bf(s);
  }
  for (int i2 = 600 + tid; i2 < 640; i2 += 256) srow[i2] = 0;  // zero pad
}

// ---------------- grid barrier: RELAXED spin, single release/acquire fences -
// (previous version did an ACQUIRE atomic load per poll -> L2-invalidate storm)
DEV void grid_barrier(unsigned* cnt, unsigned* gen, unsigned nb) {
  __syncthreads();
  if (threadIdx.x == 0) {
    unsigned g = __hip_atomic_load(gen, __ATOMIC_RELAXED, __HIP_MEMORY_SCOPE_AGENT);
    __threadfence();   // release: write back our h stores (once)
    unsigned old = __hip_atomic_fetch_add(cnt, 1u, __ATOMIC_ACQ_REL, __HIP_MEMORY_SCOPE_AGENT);
    if (old == nb - 1u) {
      __hip_atomic_store(cnt, 0u, __ATOMIC_RELAXED, __HIP_MEMORY_SCOPE_AGENT);
      __hip_atomic_fetch_add(gen, 1u, __ATOMIC_RELEASE, __HIP_MEMORY_SCOPE_AGENT);
    } else {
      while (__hip_atomic_load(gen, __ATOMIC_RELAXED, __HIP_MEMORY_SCOPE_AGENT) == g) {
        __builtin_amdgcn_s_sleep(1);
      }
    }
    __threadfence();   // acquire: invalidate once after barrier completes
  }
  __syncthreads();
}

// ---------------- bulk input-gate GEMM: gates[m][4096] = A[m][K] @ Bw[4096][K]^T
__global__ void __launch_bounds__(256, 1) gemm_ig(
    const u16* __restrict__ A, const u16* __restrict__ Bw,
    float* __restrict__ gates, int K) {
  int bid = blockIdx.x;
  int bm = bid % 9, bn = bid / 9;
  int m0 = bm * 128, n0 = bn * 128;
  int tid = threadIdx.x, w = tid >> 6, lane = tid & 63, l15 = lane & 15, lhi = lane >> 4;
  int wm = w & 1, wn = w >> 1;
  __shared__ u16 As[128][40];
  __shared__ u16 Bs[128][40];
  f32x4 acc[4][4];
  #pragma unroll
  for (int i = 0; i < 4; ++i)
    #pragma unroll
    for (int j = 0; j < 4; ++j) { f32x4 z = {0.f, 0.f, 0.f, 0.f}; acc[i][j] = z; }

  int nkt = K >> 5;
  for (int kt = 0; kt < nkt; ++kt) {
    int k0 = kt * 32;
    #pragma unroll
    for (int q = 0; q < 2; ++q) {
      int c = tid * 2 + q; int row = c >> 2; int ch = c & 3;
      int m = m0 + row;
      uint4 av{0u, 0u, 0u, 0u};
      if (m < kM) av = *(const uint4*)(A + (size_t)m * K + k0 + ch * 8);
      *(uint4*)&As[row][ch * 8] = av;
      int n = n0 + row;
      uint4 bv = *(const uint4*)(Bw + (size_t)n * K + k0 + ch * 8);
      *(uint4*)&Bs[row][ch * 8] = bv;
    }
    __syncthreads();
    short8 bfr[4];
    #pragma unroll
    for (int nt = 0; nt < 4; ++nt)
      bfr[nt] = *(const short8*)&Bs[wn * 64 + nt * 16 + l15][lhi * 8];
    #pragma unroll
    for (int mt = 0; mt < 4; ++mt) {
      short8 af = *(const short8*)&As[wm * 64 + mt * 16 + l15][lhi * 8];
      #pragma unroll
      for (int nt = 0; nt < 4; ++nt)
        acc[mt][nt] = mfma16(af, bfr[nt], acc[mt][nt]);
    }
    __syncthreads();
  }
  #pragma unroll
  for (int mt = 0; mt < 4; ++mt) {
    #pragma unroll
    for (int r = 0; r < 4; ++r) {
      int m = m0 + wm * 64 + mt * 16 + lhi * 4 + r;
      if (m < kM) {
        float* orow = gates + (size_t)m * 4096;
        #pragma unroll
        for (int nt = 0; nt < 4; ++nt) {
          int n = n0 + wn * 64 + nt * 16 + l15;
          orow[n] = acc[mt][nt][r];
        }
      }
    }
  }
}

// ---------------- LSTM recurrence: one layer, W_hh LDS-resident -------------
// 128 blocks, block p owns units [8p, 8p+8). 34 grid barriers.
__global__ void __launch_bounds__(256, 1) lstm_rec(
    const float* __restrict__ W_hh_l,   // [4096][1024] fp32, this layer
    const float* __restrict__ gates,    // [1120][4096] f32 (x-part, precomputed)
    const float* __restrict__ bias_l,   // [4096]
    u16* __restrict__ hout,             // [35*32][1024] bf16
    unsigned* bar) {
  const int p = blockIdx.x;
  const int tid = threadIdx.x;
  const int w = tid >> 6, lane = tid & 63, l15 = lane & 15, lhi = lane >> 4;
  __shared__ u16 whs[32][1032];         // rows: idx = g*8+jj -> global g*1024+8p+jj
  __shared__ float pred[4][32][33];     // [wave][w-row][batch]
  for (int i = tid; i < 32 * 256; i += 256) {
    int row = i >> 8, seg = i & 255;
    int g = row >> 3, jj = row & 7;
    const float* src = W_hh_l + ((size_t)(g * 1024 + p * 8 + jj)) * 1024 + seg * 4;
    float4 f = *(const float4*)src;
    u16 tmp[4] = {f2bf(f.x), f2bf(f.y), f2bf(f.z), f2bf(f.w)};
    *(uint2*)&whs[row][seg * 4] = *(const uint2*)tmp;
  }
  const int b = tid >> 3, jj = tid & 3 + 0;  // placeholder, real below
  const int jj2 = tid & 7;
  float bias_r[4];
  #pragma unroll
  for (int g = 0; g < 4; ++g) bias_r[g] = bias_l[g * 1024 + p * 8 + jj2];
  float c_reg = 0.f;
  const int kbase = w * 256;
  const float* gbase = gates + p * 8 + jj2 + (size_t)(tid >> 3) * 4096;

  // prefetch gx for t=0
  float gx[4];
  #pragma unroll
  for (int g = 0; g < 4; ++g) gx[g] = gbase[g * 1024];

  for (int t = 0; t < 35; ++t) {
    float gxn[4];
    if (t > 0) {
      const u16* hp = hout + (size_t)(t - 1) * 32 * 1024;
      const u16* hrow0 = hp + l15 * 1024 + lhi * 8;
      const u16* hrow1 = hp + (l15 + 16) * 1024 + lhi * 8;
      f32x4 acc00 = {0,0,0,0}, acc01 = {0,0,0,0}, acc10 = {0,0,0,0}, acc11 = {0,0,0,0};
      #pragma unroll
      for (int kk = 0; kk < 8; ++kk) {
        int k = kbase + kk * 32;
        short8 bf0 = *(const short8*)(hrow0 + k);
        short8 bf1 = *(const short8*)(hrow1 + k);
        short8 af0 = *(const short8*)&whs[l15][k + lhi * 8];
        short8 af1 = *(const short8*)&whs[16 + l15][k + lhi * 8];
        acc00 = mfma16(af0, bf0, acc00);
        acc01 = mfma16(af0, bf1, acc01);
        acc10 = mfma16(af1, bf0, acc10);
        acc11 = mfma16(af1, bf1, acc11);
      }
      // prefetch next step's gx while MFMAs drain (gates is constant data)
      if (t < 34) {
        const float* gp = gbase + (size_t)(t + 1) * 32 * 4096;
        #pragma unroll
        for (int g = 0; g < 4; ++g) gxn[g] = gp[g * 1024];
      }
      #pragma unroll
      for (int r = 0; r < 4; ++r) {
        pred[w][lhi * 4 + r][l15]       = acc00[r];
        pred[w][lhi * 4 + r][l15 + 16]  = acc01[r];
        pred[w][16 + lhi * 4 + r][l15]      = acc10[r];
        pred[w][16 + lhi * 4 + r][l15 + 16] = acc11[r];
      }
      __syncthreads();
    } else {
      const float* gp = gbase + (size_t)32 * 4096;
      #pragma unroll
      for (int g = 0; g < 4; ++g) gxn[g] = gp[g * 1024];
    }
    float pre[4];
    #pragma unroll
    for (int g = 0; g < 4; ++g) {
      float s = 0.f;
      if (t > 0) {
        int row = g * 8 + jj2;
        int bb = tid >> 3;
        s = pred[0][row][bb] + pred[1][row][bb] + pred[2][row][bb] + pred[3][row][bb];
      }
      pre[g] = s;
    }
    float iv = gx[0] + pre[0] + bias_r[0];
    float fv = gx[1] + pre[1] + bias_r[1];
    float gv = gx[2] + pre[2] + bias_r[2];
    float ov = gx[3] + pre[3] + bias_r[3];
    float cc = fsigm(fv) * c_reg + fsigm(iv) * ftanh(gv);
    float hh = fsigm(ov) * ftanh(cc);
    c_reg = cc;
    hout[((size_t)(t * 32 + (tid >> 3))) * 1024 + p * 8 + jj2] = f2bf(hh);
    if (t < 34) grid_barrier(bar, bar + 1, 128u);
    #pragma unroll
    for (int g = 0; g < 4; ++g) gx[g] = gxn[g];
  }
}

// ---------------- logits GEMM (1120x50000x1024, bf16 MFMA) + row partials ---
template <bool BW16>
__global__ void __launch_bounds__(256, 1) gemm_logits(
    const u16* __restrict__ hist2, const u16* __restrict__ linwb,
    const float* __restrict__ lin_W, const float* __restrict__ lin_b,
    float* __restrict__ out, float2* __restrict__ partials) {
  // XCD-bijective swizzle: 9 consecutive logical tiles (one B-strip) -> one XCD
  int nwg = gridDim.x, orig = blockIdx.x;
  int q = nwg >> 3, r = nwg & 7, xcd = orig & 7, off = orig >> 3;
  int bid = (xcd < r ? xcd * (q + 1) : r * (q + 1) + (xcd - r) * q) + off;
  int bm = bid % 9, bn = bid / 9;
  int m0 = bm * 128, n0 = bn * 128;
  int tid = threadIdx.x, w = tid >> 6, lane = tid & 63, l15 = lane & 15, lhi = lane >> 4;
  int wm = w & 1, wn = w >> 1;
  __shared__ u16 As[128][48];
  __shared__ u16 Bs[128][48];
  f32x4 acc[4][4];
  #pragma unroll
  for (int i = 0; i < 4; ++i)
    #pragma unroll
    for (int j = 0; j < 4; ++j) { f32x4 z = {0.f, 0.f, 0.f, 0.f}; acc[i][j] = z; }

  for (int kt = 0; kt < 32; ++kt) {
    int k0 = kt * 32;
    #pragma unroll
    for (int q2 = 0; q2 < 2; ++q2) {
      int c = tid * 2 + q2; int row = c >> 2; int ch = c & 3;
      int m = m0 + row;
      uint4 av{0u, 0u, 0u, 0u};
      if (m < kM) {
        int b = m / 35; int t = m - b * 35;
        av = *(const uint4*)(hist2 + ((size_t)(t * 32 + b) << 10) + k0 + ch * 8);
      }
      *(uint4*)&As[row][ch * 8] = av;
      int n = n0 + row;
      uint4 bv{0u, 0u, 0u, 0u};
      if (n < kVG) {
        if (BW16) {
          bv = *(const uint4*)(linwb + (size_t)n * 1024 + k0 + ch * 8);
        } else {
          const float* src = lin_W + (size_t)n * 1024 + k0 + ch * 8;
          float4 f0 = *(const float4*)(src);
          float4 f1 = *(const float4*)(src + 4);
          bv.x = (unsigned)f2bf(f0.x) | ((unsigned)f2bf(f0.y) << 16);
          bv.y = (unsigned)f2bf(f0.z) | ((unsigned)f2bf(f0.w) << 16);
          bv.z = (unsigned)f2bf(f1.x) | ((unsigned)f2bf(f1.y) << 16);
          bv.w = (unsigned)f2bf(f1.z) | ((unsigned)f2bf(f1.w) << 16);
        }
      }
      *(uint4*)&Bs[row][ch * 8] = bv;
    }
    __syncthreads();
    short8 bfr[4];
    #pragma unroll
    for (int nt = 0; nt < 4; ++nt)
      bfr[nt] = *(const short8*)&Bs[wn * 64 + nt * 16 + l15][lhi * 8];
    #pragma unroll
    for (int mt = 0; mt < 4; ++mt) {
      short8 af = *(const short8*)&As[wm * 64 + mt * 16 + l15][lhi * 8];
      #pragma unroll
      for (int nt = 0; nt < 4; ++nt)
        acc[mt][nt] = mfma16(af, bfr[nt], acc[mt][nt]);
    }
    __syncthreads();
  }
  // epilogue: store logits + per-(row, 64-col-group) max/sumexp partials
  float bcol[4]; int ncol[4];
  #pragma unroll
  for (int nt = 0; nt < 4; ++nt) {
    int n = n0 + wn * 64 + nt * 16 + l15;
    ncol[nt] = n;
    bcol[nt] = (n < kVG) ? lin_b[n] : -INFINITY;
  }
  #pragma unroll
  for (int mt = 0; mt < 4; ++mt) {
    #pragma unroll
    for (int r = 0; r < 4; ++r) {
      int m = m0 + wm * 64 + mt * 16 + lhi * 4 + r;
      float v0 = acc[mt][0][r] + bcol[0];
      float v1 = acc[mt][1][r] + bcol[1];
      float v2 = acc[mt][2][r] + bcol[2];
      float v3 = acc[mt][3][r] + bcol[3];
      bool mok = (m < kM);
      if (mok) {
        float* orow = out + (size_t)m * kVG;
        if (ncol[0] < kVG) orow[ncol[0]] = v0;
        if (ncol[1] < kVG) orow[ncol[1]] = v1;
        if (ncol[2] < kVG) orow[ncol[2]] = v2;
        if (ncol[3] < kVG) orow[ncol[3]] = v3;
      }
      float mx = fmaxf(fmaxf(v0, v1), fmaxf(v2, v3));
      #pragma unroll
      for (int d2 = 1; d2 < 16; d2 <<= 1) mx = fmaxf(mx, __shfl_xor(mx, d2, 64));
      float sv = 0.f;
      sv += (v0 > -1e30f) ? fexp(v0 - mx) : 0.f;
      sv += (v1 > -1e30f) ? fexp(v1 - mx) : 0.f;
      sv += (v2 > -1e30f) ? fexp(v2 - mx) : 0.f;
      sv += (v3 > -1e30f) ? fexp(v3 - mx) : 0.f;
      #pragma unroll
      for (int d2 = 1; d2 < 16; d2 <<= 1) sv += __shfl_xor(sv, d2, 64);
      if (mok && l15 == 0)
        partials[(size_t)m * 784 + bn * 2 + wn] = make_float2(mx, sv);
    }
  }
}

// ---------------- row logsumexp reduce --------------------------------------
__global__ void reduce_rows(const float2* __restrict__ partials, float* __restrict__ lse) {
  int m = blockIdx.x, tid = threadIdx.x;
  float mx = -INFINITY, s = 0.f;
  for (int j = tid; j < 782; j += 256) {
    float2 p = partials[(size_t)m * 784 + j];
    if (p.x > mx) { s = s * fexp(mx - p.x) + p.y; mx = p.x; }
    else          { s += p.y * fexp(p.x - mx); }
  }
  for (int d = 1; d < 64; d <<= 1) {
    float omx = __shfl_xor(mx, d, 64);
    float os  = __shfl_xor(s, d, 64);
    if (omx > mx) { s = s * fexp(mx - omx) + os; mx = omx; }
    else          { s += os * fexp(omx - mx); }
  }
  __shared__ float smx[4], ssum[4];
  int w = tid >> 6;
  if ((tid & 63) == 0) { smx[w] = mx; ssum[w] = s; }
  __syncthreads();
  if (tid == 0) {
    for (int i = 1; i < 4; ++i) {
      float omx = smx[i], os = ssum[i];
      if (omx > mx) { s = s * fexp(mx - omx) + os; mx = omx; }
      else          { s += os * fexp(omx - mx); }
    }
    lse[m] = mx + logf(s);
  }
}

// ---------------- in-place log_softmax subtract -----------------------------
__global__ void sub_lse(float* __restrict__ out, const float* __restrict__ lse) {
  const int total4 = 14000000;  // 1120*50000/4
  for (int i = blockIdx.x * blockDim.x + threadIdx.x; i < total4; i += gridDim.x * blockDim.x) {
    int m = i / 12500;
    float4 v = ((float4*)out)[i];
    float L = lse[m];
    v.x -= L; v.y -= L; v.z -= L; v.w -= L;
    ((float4*)out)[i] = v;
  }
}

// ---------------- launch ----------------------------------------------------
extern "C" void kernel_launch(void* const* d_in, const int* in_sizes, int n_in,
                              void* d_out, int out_size, void* d_ws, size_t ws_size,
                              hipStream_t stream) {
  const int*   x_indices  = (const int*)d_in[0];
  const int*   edge_index = (const int*)d_in[1];
  const float* X          = (const float*)d_in[2];
  const float* gat_W      = (const float*)d_in[3];
  const float* att_src    = (const float*)d_in[4];
  const float* att_dst    = (const float*)d_in[5];
  const float* gat_bias   = (const float*)d_in[6];
  const float* W_ih0      = (const float*)d_in[7];
  const float* W_ih_rest  = (const float*)d_in[8];
  const float* W_hh       = (const float*)d_in[9];
  const float* b_ih       = (const float*)d_in[10];
  const float* b_hh       = (const float*)d_in[11];
  const float* lin_W      = (const float*)d_in[12];
  const float* lin_b      = (const float*)d_in[13];
  float* out = (float*)d_out;
  char* ws = (char*)d_ws;

  unsigned* bar      = (unsigned*)(ws + OFF_BAR);
  float*    ws_src   = (float*)(ws + OFF_WSRC);
  float*    ws_dst   = (float*)(ws + OFF_WDST);
  float*    bias_sum = (float*)(ws + OFF_BIAS);
  u16*      sig      = (u16*)(ws + OFF_SIG);
  u16*      wx0      = (u16*)(ws + OFF_WX0);
  u16*      wx12     = (u16*)(ws + OFF_WX12);
  float*    gates    = (float*)(ws + OFF_GATES);
  u16*      hist     = (u16*)(ws + OFF_HIST);
  float2*   partials = (float2*)(ws + OFF_PART);
  float*    lse      = (float*)(ws + OFF_LSE);
  u16*      linwb    = (u16*)(ws + OFF_LINWB);
  bool use_bw = (ws_size >= kNeedBW);

  u16* hist0 = hist;
  u16* hist1 = hist + (size_t)35 * 32 * 1024;
  u16* hist2 = hist + (size_t)2 * 35 * 32 * 1024;

  hipMemsetAsync(ws + OFF_BAR, 0, 256, stream);
  prep_small<<<64, 256, 0, stream>>>(gat_W, att_src, att_dst, b_ih, b_hh,
                                     ws_src, ws_dst, bias_sum);
  wx_prep<<<1024, 256, 0, stream>>>(W_ih0, W_ih_rest, wx0, wx12);
  if (use_bw) wb_conv<<<2048, 256, 0, stream>>>(lin_W, linwb);
  gat_kernel<<<kG, 256, 0, stream>>>(x_indices, edge_index, X, gat_W, gat_bias,
                                     ws_src, ws_dst, sig);
  // layer 0
  gemm_ig<<<288, 256, 0, stream>>>(sig, wx0, gates, 640);
  lstm_rec<<<128, 256, 0, stream>>>(W_hh, gates, bias_sum, hist0, bar);
  // layer 1
  gemm_ig<<<288, 256, 0, stream>>>(hist0, wx12, gates, 1024);
  lstm_rec<<<128, 256, 0, stream>>>(W_hh + (size_t)4096 * 1024, gates,
                                    bias_sum + 4096, hist1, bar);
  // layer 2
  gemm_ig<<<288, 256, 0, stream>>>(hist1, wx12 + (size_t)4096 * 1024, gates, 1024);
  lstm_rec<<<128, 256, 0, stream>>>(W_hh + (size_t)2 * 4096 * 1024, gates,
                                    bias_sum + 8192, hist2, bar);
  // logits + log_softmax
  if (use_bw)
    gemm_logits<true><<<9 * 391, 256, 0, stream>>>(hist2, linwb, lin_W, lin_b, out, partials);
  else
    gemm_logits<false><<<9 * 391, 256, 0, stream>>>(hist2, nullptr, lin_W, lin_b, out, partials);
  reduce_rows<<<kG, 256, 0, stream>>>(partials, lse);
  sub_lse<<<2048, 256, 0, stream>>>(out, lse);
}

// Round 4
// 1857.584 us; speedup vs baseline: 1.4048x; 1.0095x over previous
//
#include <hip/hip_runtime.h>

#define DEV __device__ __forceinline__

typedef __attribute__((ext_vector_type(8))) short short8;
typedef __attribute__((ext_vector_type(4))) float f32x4;
typedef unsigned short u16;

constexpr int kV = 80000, kD = 300, kNN = 32, kEE = 64, kHH = 4, kCC = 75;
constexpr int kB = 32, kT = 35, kU = 1024, kVG = 50000;
constexpr int kG = kB * kT;          // 1120
constexpr int kM = kG;

constexpr size_t alignup(size_t x) { return (x + 255) & ~size_t(255); }
constexpr size_t OFF_BAR   = 0;
constexpr size_t OFF_WSRC  = 256;
constexpr size_t OFF_WDST  = alignup(OFF_WSRC + 1200 * 4);
constexpr size_t OFF_BIAS  = alignup(OFF_WDST + 1200 * 4);
constexpr size_t OFF_SIG   = alignup(OFF_BIAS + 3 * 4096 * 4);
constexpr size_t OFF_WX0   = alignup(OFF_SIG + (size_t)35 * 32 * 640 * 2);
constexpr size_t OFF_WX12  = alignup(OFF_WX0 + (size_t)4096 * 640 * 2);
constexpr size_t OFF_HIST  = alignup(OFF_WX12 + (size_t)2 * 4096 * 1024 * 2);
constexpr size_t OFF_PART  = alignup(OFF_HIST + (size_t)3 * 35 * 32 * 1024 * 2);
constexpr size_t OFF_LSE   = alignup(OFF_PART + (size_t)1120 * 784 * 8);
constexpr size_t OFF_LINWB = alignup(OFF_LSE + 1120 * 4);
constexpr size_t kLinWBytes = (size_t)kVG * 1024 * 2;
constexpr size_t kNeedBW   = OFF_LINWB + kLinWBytes;

DEV u16 f2bf(float f) {
  union { float f; unsigned u; } v; v.f = f;
  unsigned r = v.u + 0x7fffu + ((v.u >> 16) & 1u);
  return (u16)(r >> 16);
}
// fast transcendentals via v_exp_f32 (2^x) + v_rcp_f32; abs tolerance is ~0.2
DEV float fexp(float x) { return __builtin_amdgcn_exp2f(x * 1.4426950408889634f); }
DEV float fsigm(float x) {
  float t = __builtin_amdgcn_exp2f(-1.4426950408889634f * x);
  return __builtin_amdgcn_rcpf(1.f + t);
}
DEV float ftanh(float x) {
  float xc = fminf(fmaxf(x, -20.f), 20.f);
  float t = __builtin_amdgcn_exp2f(2.8853900817779268f * xc);
  return (t - 1.f) * __builtin_amdgcn_rcpf(t + 1.f);
}
DEV f32x4 mfma16(short8 a, short8 b, f32x4 c) {
  return __builtin_amdgcn_mfma_f32_16x16x32_bf16(a, b, c, 0, 0, 0);
}

// ---------------- prep: ws_src/ws_dst (W @ att vectors), bias sums ----------
__global__ void prep_small(const float* __restrict__ gat_W,
                           const float* __restrict__ att_src,
                           const float* __restrict__ att_dst,
                           const float* __restrict__ b_ih,
                           const float* __restrict__ b_hh,
                           float* __restrict__ ws_src, float* __restrict__ ws_dst,
                           float* __restrict__ bias_sum) {
  int total = 1200 + 1200 + 3 * 4096;
  for (int i = blockIdx.x * blockDim.x + threadIdx.x; i < total; i += gridDim.x * blockDim.x) {
    if (i < 1200) {
      int d = i >> 2, h = i & 3;
      float s = 0.f;
      for (int c = 0; c < kCC; ++c) s += gat_W[d * 300 + h * kCC + c] * att_src[h * kCC + c];
      ws_src[i] = s;
    } else if (i < 2400) {
      int j = i - 1200; int d = j >> 2, h = j & 3;
      float s = 0.f;
      for (int c = 0; c < kCC; ++c) s += gat_W[d * 300 + h * kCC + c] * att_dst[h * kCC + c];
      ws_dst[j] = s;
    } else {
      int j = i - 2400;
      bias_sum[j] = b_ih[j] + b_hh[j];
    }
  }
}

// ---------------- prep: bf16 input-transform weights ------------------------
__global__ void wx_prep(const float* __restrict__ W_ih0,
                        const float* __restrict__ W_ih_rest,
                        u16* __restrict__ wx0, u16* __restrict__ wx12) {
  const int n0 = 4096 * 640;
  const int n12 = 2 * 4096 * 1024;
  int total = n0 + n12;
  for (int i = blockIdx.x * blockDim.x + threadIdx.x; i < total; i += gridDim.x * blockDim.x) {
    if (i < n0) {
      int row = i / 640, col = i - row * 640;
      float v = (col < 600) ? W_ih0[row * 600 + col] : 0.f;
      wx0[i] = f2bf(v);
    } else {
      int j = i - n0;
      wx12[j] = f2bf(W_ih_rest[j]);
    }
  }
}

// ---------------- prep: bf16 copy of lin_W (halves GEMM B traffic) ----------
__global__ void wb_conv(const float* __restrict__ W, u16* __restrict__ Wb) {
  const long n = (long)kVG * 1024;
  long stride = (long)gridDim.x * blockDim.x * 8;
  for (long i = (long)(blockIdx.x * blockDim.x + threadIdx.x) * 8; i < n; i += stride) {
    float4 a = *(const float4*)(W + i);
    float4 b = *(const float4*)(W + i + 4);
    u16 t[8] = {f2bf(a.x), f2bf(a.y), f2bf(a.z), f2bf(a.w),
                f2bf(b.x), f2bf(b.y), f2bf(b.z), f2bf(b.w)};
    *(uint4*)(Wb + i) = *(const uint4*)t;
  }
}

// ---------------- GAT (node-0 only, factored attention) ---------------------
__global__ void __launch_bounds__(256) gat_kernel(
    const int* __restrict__ x_indices, const int* __restrict__ edge_index,
    const float* __restrict__ X, const float* __restrict__ gat_W,
    const float* __restrict__ gat_bias, const float* __restrict__ ws_src,
    const float* __restrict__ ws_dst, u16* __restrict__ sig) {
  __shared__ float xs[32][301];
  __shared__ float a_s[32][4];
  __shared__ float a_d0[4];
  __shared__ float alpha[4][32];
  __shared__ float xw[4][301];
  __shared__ int allowed[32];
  int g = blockIdx.x, tid = threadIdx.x;
  const int* idx = x_indices + g * 32;
  for (int i = tid; i < 32 * 300; i += 256) {
    int j = i / 300, d2 = i - j * 300;
    xs[j][d2] = X[(size_t)idx[j] * 300 + d2];
  }
  if (tid < 32) allowed[tid] = (tid == 0) ? 1 : 0;
  __syncthreads();
  if (tid < 128) {
    int j = tid >> 2, h = tid & 3;
    float s = 0.f;
    for (int d2 = 0; d2 < 300; ++d2) s += xs[j][d2] * ws_src[d2 * 4 + h];
    a_s[j][h] = s;
  } else if (tid < 132) {
    int h = tid - 128; float s = 0.f;
    for (int d2 = 0; d2 < 300; ++d2) s += xs[0][d2] * ws_dst[d2 * 4 + h];
    a_d0[h] = s;
  } else if (tid >= 192) {
    int e = tid - 192;
    int src = edge_index[g * 128 + e];
    int dst = edge_index[g * 128 + 64 + e];
    if (dst == 0) allowed[src] = 1;
  }
  __syncthreads();
  if (tid < 4) {
    int h = tid;
    float ev[32];
    float mx = -1e30f;
    #pragma unroll
    for (int j = 0; j < 32; ++j) {
      float v = a_d0[h] + a_s[j][h];
      v = (v > 0.f) ? v : 0.2f * v;
      v = allowed[j] ? v : -1e9f;
      ev[j] = v; mx = fmaxf(mx, v);
    }
    float ssum = 0.f;
    #pragma unroll
    for (int j = 0; j < 32; ++j) { float p = fexp(ev[j] - mx); ev[j] = p; ssum += p; }
    float inv = 1.f / ssum;
    #pragma unroll
    for (int j = 0; j < 32; ++j) alpha[h][j] = ev[j] * inv;
  }
  __syncthreads();
  for (int i = tid; i < 4 * 300; i += 256) {
    int h = i / 300, d2 = i - h * 300;
    float s = 0.f;
    #pragma unroll
    for (int j = 0; j < 32; ++j) s += alpha[h][j] * xs[j][d2];
    xw[h][d2] = s;
  }
  __syncthreads();
  int t = g % 35, b = g / 35;
  u16* srow = sig + ((size_t)t * 32 + b) * 640;
  for (int hc = tid; hc < 300; hc += 256) {
    srow[hc] = f2bf(xs[0][hc]);           // curr_emb = X[idx 0]
    int h = hc / 75;
    float s = gat_bias[hc];
    for (int d2 = 0; d2 < 300; ++d2) s += xw[h][d2] * gat_W[d2 * 300 + hc];
    srow[300 + hc] = f2bf(s);
  }
  for (int i2 = 600 + tid; i2 < 640; i2 += 256) srow[i2] = 0;  // zero pad
}

// ---------------- grid barrier: relaxed spin, single release/acquire fences -
DEV void grid_barrier(unsigned* cnt, unsigned* gen, unsigned nb) {
  __syncthreads();
  if (threadIdx.x == 0) {
    unsigned g = __hip_atomic_load(gen, __ATOMIC_RELAXED, __HIP_MEMORY_SCOPE_AGENT);
    __threadfence();   // release: write back our h stores (once)
    unsigned old = __hip_atomic_fetch_add(cnt, 1u, __ATOMIC_ACQ_REL, __HIP_MEMORY_SCOPE_AGENT);
    if (old == nb - 1u) {
      __hip_atomic_store(cnt, 0u, __ATOMIC_RELAXED, __HIP_MEMORY_SCOPE_AGENT);
      __hip_atomic_fetch_add(gen, 1u, __ATOMIC_RELEASE, __HIP_MEMORY_SCOPE_AGENT);
    } else {
      while (__hip_atomic_load(gen, __ATOMIC_RELAXED, __HIP_MEMORY_SCOPE_AGENT) == g) {
        __builtin_amdgcn_s_sleep(1);
      }
    }
    __threadfence();   // acquire: invalidate once after barrier completes
  }
  __syncthreads();
}

// ---------------- fused 3-layer LSTM wavefront ------------------------------
// 192 blocks = 3 layers x 64 unit-blocks (16 units each). 37 steps, 36 barriers.
// Layer l at step s computes t = s - l. x-part weights streamed from L2,
// W_hh slice LDS-resident (bf16). Wave w computes gate w (i,f,g,o).
__global__ void __launch_bounds__(256, 1) lstm_wave(
    const u16* __restrict__ sig, const u16* __restrict__ wx0,
    const u16* __restrict__ wx12, const float* __restrict__ W_hh,
    const float* __restrict__ bias_sum, u16* __restrict__ hist,
    unsigned* __restrict__ bar) {
  const int bid = blockIdx.x;
  const int l = bid >> 6;
  const int p = bid & 63;
  const int u0 = p * 16;
  const int tid = threadIdx.x;
  const int w = tid >> 6, lane = tid & 63, l15 = lane & 15, lhi = lane >> 4;

  __shared__ u16 whs[64][1032];    // W_hh rows: row = gate*16 + unit (bf16)
  __shared__ float gbuf[64][33];   // gate staging for pointwise

  // load W_hh slice -> LDS (thread tid owns float4 column-segment tid*4 of every row)
  for (int n = 0; n < 64; ++n) {
    int g = n >> 4, j = n & 15;
    const float* src = W_hh + ((size_t)l * 4096 + g * 1024 + u0 + j) * 1024 + tid * 4;
    float4 f = *(const float4*)src;
    u16 tmp[4] = {f2bf(f.x), f2bf(f.y), f2bf(f.z), f2bf(f.w)};
    *(uint2*)&whs[n][tid * 4] = *(const uint2*)tmp;
  }
  __syncthreads();

  const int Kx = (l == 0) ? 640 : 1024;
  const u16* wx = (l == 0) ? wx0 : (wx12 + (size_t)(l - 1) * 4096 * 1024);
  const u16* wxrow = wx + ((size_t)(w * 1024 + u0 + l15)) * Kx + lhi * 8;

  const int pj = tid & 15, pb = tid >> 4;   // pointwise: unit pj, batches pb, pb+16
  float bias_r[4];
  #pragma unroll
  for (int g = 0; g < 4; ++g) bias_r[g] = bias_sum[l * 4096 + g * 1024 + u0 + pj];
  float c0 = 0.f, c1 = 0.f;

  u16* histL = hist + (size_t)l * 35 * 32 * 1024;
  const u16* xsrc = (l == 0) ? sig : hist + (size_t)(l - 1) * 35 * 32 * 1024;

  for (int s = 0; s < 37; ++s) {
    int t = s - l;
    if (t >= 0 && t < 35) {
      f32x4 acc0 = {0.f, 0.f, 0.f, 0.f}, acc1 = {0.f, 0.f, 0.f, 0.f};
      // x-part: A = W_ih rows (global, L2-hot), B = x rows (prev layer h / sig)
      const u16* xrow = xsrc + (size_t)t * 32 * Kx;
      const u16* b0p = xrow + l15 * Kx + lhi * 8;
      const u16* b1p = xrow + (l15 + 16) * Kx + lhi * 8;
      #pragma unroll 4
      for (int k = 0; k < Kx; k += 32) {
        short8 af = *(const short8*)(wxrow + k);
        short8 b0 = *(const short8*)(b0p + k);
        short8 b1 = *(const short8*)(b1p + k);
        acc0 = mfma16(af, b0, acc0);
        acc1 = mfma16(af, b1, acc1);
      }
      // h-part: A = W_hh rows (LDS), B = own h_{t-1}
      if (t > 0) {
        const u16* hrow = histL + (size_t)(t - 1) * 32 * 1024;
        const u16* h0p = hrow + l15 * 1024 + lhi * 8;
        const u16* h1p = hrow + (l15 + 16) * 1024 + lhi * 8;
        #pragma unroll 4
        for (int k = 0; k < 1024; k += 32) {
          short8 af = *(const short8*)&whs[w * 16 + l15][k + lhi * 8];
          short8 b0 = *(const short8*)(h0p + k);
          short8 b1 = *(const short8*)(h1p + k);
          acc0 = mfma16(af, b0, acc0);
          acc1 = mfma16(af, b1, acc1);
        }
      }
      #pragma unroll
      for (int r = 0; r < 4; ++r) {
        gbuf[w * 16 + lhi * 4 + r][l15]      = acc0[r];
        gbuf[w * 16 + lhi * 4 + r][l15 + 16] = acc1[r];
      }
      __syncthreads();
      float iv0 = gbuf[pj][pb]      + bias_r[0];
      float fv0 = gbuf[16 + pj][pb] + bias_r[1];
      float gv0 = gbuf[32 + pj][pb] + bias_r[2];
      float ov0 = gbuf[48 + pj][pb] + bias_r[3];
      float iv1 = gbuf[pj][pb + 16]      + bias_r[0];
      float fv1 = gbuf[16 + pj][pb + 16] + bias_r[1];
      float gv1 = gbuf[32 + pj][pb + 16] + bias_r[2];
      float ov1 = gbuf[48 + pj][pb + 16] + bias_r[3];
      float cc0 = fsigm(fv0) * c0 + fsigm(iv0) * ftanh(gv0);
      float hh0 = fsigm(ov0) * ftanh(cc0); c0 = cc0;
      float cc1 = fsigm(fv1) * c1 + fsigm(iv1) * ftanh(gv1);
      float hh1 = fsigm(ov1) * ftanh(cc1); c1 = cc1;
      histL[((size_t)t * 32 + pb) * 1024 + u0 + pj]      = f2bf(hh0);
      histL[((size_t)t * 32 + pb + 16) * 1024 + u0 + pj] = f2bf(hh1);
    }
    if (s < 36) grid_barrier(bar, bar + 1, 192u);
  }
}

// ---------------- logits GEMM (1120x50000x1024, bf16 MFMA) + row partials ---
template <bool BW16>
__global__ void __launch_bounds__(256, 1) gemm_logits(
    const u16* __restrict__ hist2, const u16* __restrict__ linwb,
    const float* __restrict__ lin_W, const float* __restrict__ lin_b,
    float* __restrict__ out, float2* __restrict__ partials) {
  // XCD-bijective swizzle: 9 consecutive logical tiles (one B-strip) -> one XCD
  int nwg = gridDim.x, orig = blockIdx.x;
  int q = nwg >> 3, r = nwg & 7, xcd = orig & 7, off = orig >> 3;
  int bid = (xcd < r ? xcd * (q + 1) : r * (q + 1) + (xcd - r) * q) + off;
  int bm = bid % 9, bn = bid / 9;
  int m0 = bm * 128, n0 = bn * 128;
  int tid = threadIdx.x, w = tid >> 6, lane = tid & 63, l15 = lane & 15, lhi = lane >> 4;
  int wm = w & 1, wn = w >> 1;
  __shared__ u16 As[128][48];
  __shared__ u16 Bs[128][48];
  f32x4 acc[4][4];
  #pragma unroll
  for (int i = 0; i < 4; ++i)
    #pragma unroll
    for (int j = 0; j < 4; ++j) { f32x4 z = {0.f, 0.f, 0.f, 0.f}; acc[i][j] = z; }

  for (int kt = 0; kt < 32; ++kt) {
    int k0 = kt * 32;
    #pragma unroll
    for (int q2 = 0; q2 < 2; ++q2) {
      int c = tid * 2 + q2; int row = c >> 2; int ch = c & 3;
      int m = m0 + row;
      uint4 av{0u, 0u, 0u, 0u};
      if (m < kM) {
        int b = m / 35; int t = m - b * 35;
        av = *(const uint4*)(hist2 + ((size_t)(t * 32 + b) << 10) + k0 + ch * 8);
      }
      *(uint4*)&As[row][ch * 8] = av;
      int n = n0 + row;
      uint4 bv{0u, 0u, 0u, 0u};
      if (n < kVG) {
        if (BW16) {
          bv = *(const uint4*)(linwb + (size_t)n * 1024 + k0 + ch * 8);
        } else {
          const float* src = lin_W + (size_t)n * 1024 + k0 + ch * 8;
          float4 f0 = *(const float4*)(src);
          float4 f1 = *(const float4*)(src + 4);
          bv.x = (unsigned)f2bf(f0.x) | ((unsigned)f2bf(f0.y) << 16);
          bv.y = (unsigned)f2bf(f0.z) | ((unsigned)f2bf(f0.w) << 16);
          bv.z = (unsigned)f2bf(f1.x) | ((unsigned)f2bf(f1.y) << 16);
          bv.w = (unsigned)f2bf(f1.z) | ((unsigned)f2bf(f1.w) << 16);
        }
      }
      *(uint4*)&Bs[row][ch * 8] = bv;
    }
    __syncthreads();
    short8 bfr[4];
    #pragma unroll
    for (int nt = 0; nt < 4; ++nt)
      bfr[nt] = *(const short8*)&Bs[wn * 64 + nt * 16 + l15][lhi * 8];
    #pragma unroll
    for (int mt = 0; mt < 4; ++mt) {
      short8 af = *(const short8*)&As[wm * 64 + mt * 16 + l15][lhi * 8];
      #pragma unroll
      for (int nt = 0; nt < 4; ++nt)
        acc[mt][nt] = mfma16(af, bfr[nt], acc[mt][nt]);
    }
    __syncthreads();
  }
  // epilogue: store logits + per-(row, 64-col-group) max/sumexp partials
  float bcol[4]; int ncol[4];
  #pragma unroll
  for (int nt = 0; nt < 4; ++nt) {
    int n = n0 + wn * 64 + nt * 16 + l15;
    ncol[nt] = n;
    bcol[nt] = (n < kVG) ? lin_b[n] : -INFINITY;
  }
  #pragma unroll
  for (int mt = 0; mt < 4; ++mt) {
    #pragma unroll
    for (int r = 0; r < 4; ++r) {
      int m = m0 + wm * 64 + mt * 16 + lhi * 4 + r;
      float v0 = acc[mt][0][r] + bcol[0];
      float v1 = acc[mt][1][r] + bcol[1];
      float v2 = acc[mt][2][r] + bcol[2];
      float v3 = acc[mt][3][r] + bcol[3];
      bool mok = (m < kM);
      if (mok) {
        float* orow = out + (size_t)m * kVG;
        if (ncol[0] < kVG) orow[ncol[0]] = v0;
        if (ncol[1] < kVG) orow[ncol[1]] = v1;
        if (ncol[2] < kVG) orow[ncol[2]] = v2;
        if (ncol[3] < kVG) orow[ncol[3]] = v3;
      }
      float mx = fmaxf(fmaxf(v0, v1), fmaxf(v2, v3));
      #pragma unroll
      for (int d2 = 1; d2 < 16; d2 <<= 1) mx = fmaxf(mx, __shfl_xor(mx, d2, 64));
      float sv = 0.f;
      sv += (v0 > -1e30f) ? fexp(v0 - mx) : 0.f;
      sv += (v1 > -1e30f) ? fexp(v1 - mx) : 0.f;
      sv += (v2 > -1e30f) ? fexp(v2 - mx) : 0.f;
      sv += (v3 > -1e30f) ? fexp(v3 - mx) : 0.f;
      #pragma unroll
      for (int d2 = 1; d2 < 16; d2 <<= 1) sv += __shfl_xor(sv, d2, 64);
      if (mok && l15 == 0)
        partials[(size_t)m * 784 + bn * 2 + wn] = make_float2(mx, sv);
    }
  }
}

// ---------------- row logsumexp reduce --------------------------------------
__global__ void reduce_rows(const float2* __restrict__ partials, float* __restrict__ lse) {
  int m = blockIdx.x, tid = threadIdx.x;
  float mx = -INFINITY, s = 0.f;
  for (int j = tid; j < 782; j += 256) {
    float2 p = partials[(size_t)m * 784 + j];
    if (p.x > mx) { s = s * fexp(mx - p.x) + p.y; mx = p.x; }
    else          { s += p.y * fexp(p.x - mx); }
  }
  for (int d = 1; d < 64; d <<= 1) {
    float omx = __shfl_xor(mx, d, 64);
    float os  = __shfl_xor(s, d, 64);
    if (omx > mx) { s = s * fexp(mx - omx) + os; mx = omx; }
    else          { s += os * fexp(omx - mx); }
  }
  __shared__ float smx[4], ssum[4];
  int w = tid >> 6;
  if ((tid & 63) == 0) { smx[w] = mx; ssum[w] = s; }
  __syncthreads();
  if (tid == 0) {
    for (int i = 1; i < 4; ++i) {
      float omx = smx[i], os = ssum[i];
      if (omx > mx) { s = s * fexp(mx - omx) + os; mx = omx; }
      else          { s += os * fexp(omx - mx); }
    }
    lse[m] = mx + logf(s);
  }
}

// ---------------- in-place log_softmax subtract -----------------------------
__global__ void sub_lse(float* __restrict__ out, const float* __restrict__ lse) {
  const int total4 = 14000000;  // 1120*50000/4
  for (int i = blockIdx.x * blockDim.x + threadIdx.x; i < total4; i += gridDim.x * blockDim.x) {
    int m = i / 12500;
    float4 v = ((float4*)out)[i];
    float L = lse[m];
    v.x -= L; v.y -= L; v.z -= L; v.w -= L;
    ((float4*)out)[i] = v;
  }
}

// ---------------- launch ----------------------------------------------------
extern "C" void kernel_launch(void* const* d_in, const int* in_sizes, int n_in,
                              void* d_out, int out_size, void* d_ws, size_t ws_size,
                              hipStream_t stream) {
  const int*   x_indices  = (const int*)d_in[0];
  const int*   edge_index = (const int*)d_in[1];
  const float* X          = (const float*)d_in[2];
  const float* gat_W      = (const float*)d_in[3];
  const float* att_src    = (const float*)d_in[4];
  const float* att_dst    = (const float*)d_in[5];
  const float* gat_bias   = (const float*)d_in[6];
  const float* W_ih0      = (const float*)d_in[7];
  const float* W_ih_rest  = (const float*)d_in[8];
  const float* W_hh       = (const float*)d_in[9];
  const float* b_ih       = (const float*)d_in[10];
  const float* b_hh       = (const float*)d_in[11];
  const float* lin_W      = (const float*)d_in[12];
  const float* lin_b      = (const float*)d_in[13];
  float* out = (float*)d_out;
  char* ws = (char*)d_ws;

  unsigned* bar      = (unsigned*)(ws + OFF_BAR);
  float*    ws_src   = (float*)(ws + OFF_WSRC);
  float*    ws_dst   = (float*)(ws + OFF_WDST);
  float*    bias_sum = (float*)(ws + OFF_BIAS);
  u16*      sig      = (u16*)(ws + OFF_SIG);
  u16*      wx0      = (u16*)(ws + OFF_WX0);
  u16*      wx12     = (u16*)(ws + OFF_WX12);
  u16*      hist     = (u16*)(ws + OFF_HIST);
  float2*   partials = (float2*)(ws + OFF_PART);
  float*    lse      = (float*)(ws + OFF_LSE);
  u16*      linwb    = (u16*)(ws + OFF_LINWB);
  bool use_bw = (ws_size >= kNeedBW);

  u16* hist2 = hist + (size_t)2 * 35 * 32 * 1024;

  hipMemsetAsync(ws + OFF_BAR, 0, 256, stream);
  prep_small<<<64, 256, 0, stream>>>(gat_W, att_src, att_dst, b_ih, b_hh,
                                     ws_src, ws_dst, bias_sum);
  wx_prep<<<1024, 256, 0, stream>>>(W_ih0, W_ih_rest, wx0, wx12);
  if (use_bw) wb_conv<<<2048, 256, 0, stream>>>(lin_W, linwb);
  gat_kernel<<<kG, 256, 0, stream>>>(x_indices, edge_index, X, gat_W, gat_bias,
                                     ws_src, ws_dst, sig);
  // fused 3-layer LSTM wavefront (one persistent kernel, 36 grid barriers)
  lstm_wave<<<192, 256, 0, stream>>>(sig, wx0, wx12, W_hh, bias_sum, hist, bar);
  // logits + log_softmax
  if (use_bw)
    gemm_logits<true><<<9 * 391, 256, 0, stream>>>(hist2, linwb, lin_W, lin_b, out, partials);
  else
    gemm_logits<false><<<9 * 391, 256, 0, stream>>>(hist2, nullptr, lin_W, lin_b, out, partials);
  reduce_rows<<<kG, 256, 0, stream>>>(partials, lse);
  sub_lse<<<2048, 256, 0, stream>>>(out, lse);
}

// Round 5
// 1845.252 us; speedup vs baseline: 1.4142x; 1.0067x over previous
//
#include <hip/hip_runtime.h>

#define DEV __device__ __forceinline__

typedef __attribute__((ext_vector_type(8))) short short8;
typedef __attribute__((ext_vector_type(4))) float f32x4;
typedef unsigned short u16;

constexpr int kV = 80000, kD = 300, kNN = 32, kEE = 64, kHH = 4, kCC = 75;
constexpr int kB = 32, kT = 35, kU = 1024, kVG = 50000;
constexpr int kG = kB * kT;          // 1120
constexpr int kM = kG;

constexpr size_t alignup(size_t x) { return (x + 255) & ~size_t(255); }
constexpr size_t OFF_BAR   = 0;       // 128 flag slots (1024 B reserved)
constexpr size_t OFF_WSRC  = 1024;
constexpr size_t OFF_WDST  = alignup(OFF_WSRC + 1200 * 4);
constexpr size_t OFF_BIAS  = alignup(OFF_WDST + 1200 * 4);
constexpr size_t OFF_SIG   = alignup(OFF_BIAS + 3 * 4096 * 4);
constexpr size_t OFF_WX0   = alignup(OFF_SIG + (size_t)35 * 32 * 640 * 2);
constexpr size_t OFF_WX12  = alignup(OFF_WX0 + (size_t)4096 * 640 * 2);
constexpr size_t OFF_GATES = alignup(OFF_WX12 + (size_t)2 * 4096 * 1024 * 2);
constexpr size_t OFF_HIST  = alignup(OFF_GATES + (size_t)1120 * 4096 * 4);
constexpr size_t OFF_PART  = alignup(OFF_HIST + (size_t)3 * 35 * 32 * 1024 * 2);
constexpr size_t OFF_LSE   = alignup(OFF_PART + (size_t)1120 * 784 * 8);
constexpr size_t OFF_LINWB = alignup(OFF_LSE + 1120 * 4);
constexpr size_t kLinWBytes = (size_t)kVG * 1024 * 2;
constexpr size_t kNeedBW   = OFF_LINWB + kLinWBytes;

DEV u16 f2bf(float f) {
  union { float f; unsigned u; } v; v.f = f;
  unsigned r = v.u + 0x7fffu + ((v.u >> 16) & 1u);
  return (u16)(r >> 16);
}
// fast transcendentals via v_exp_f32 (2^x) + v_rcp_f32; abs tolerance is ~0.2
DEV float fexp(float x) { return __builtin_amdgcn_exp2f(x * 1.4426950408889634f); }
DEV float fsigm(float x) {
  float t = __builtin_amdgcn_exp2f(-1.4426950408889634f * x);
  return __builtin_amdgcn_rcpf(1.f + t);
}
DEV float ftanh(float x) {
  float xc = fminf(fmaxf(x, -20.f), 20.f);
  float t = __builtin_amdgcn_exp2f(2.8853900817779268f * xc);
  return (t - 1.f) * __builtin_amdgcn_rcpf(t + 1.f);
}
DEV f32x4 mfma16(short8 a, short8 b, f32x4 c) {
  return __builtin_amdgcn_mfma_f32_16x16x32_bf16(a, b, c, 0, 0, 0);
}

// ---------------- prep: ws_src/ws_dst (W @ att vectors), bias sums ----------
__global__ void prep_small(const float* __restrict__ gat_W,
                           const float* __restrict__ att_src,
                           const float* __restrict__ att_dst,
                           const float* __restrict__ b_ih,
                           const float* __restrict__ b_hh,
                           float* __restrict__ ws_src, float* __restrict__ ws_dst,
                           float* __restrict__ bias_sum) {
  int total = 1200 + 1200 + 3 * 4096;
  for (int i = blockIdx.x * blockDim.x + threadIdx.x; i < total; i += gridDim.x * blockDim.x) {
    if (i < 1200) {
      int d = i >> 2, h = i & 3;
      float s = 0.f;
      for (int c = 0; c < kCC; ++c) s += gat_W[d * 300 + h * kCC + c] * att_src[h * kCC + c];
      ws_src[i] = s;
    } else if (i < 2400) {
      int j = i - 1200; int d = j >> 2, h = j & 3;
      float s = 0.f;
      for (int c = 0; c < kCC; ++c) s += gat_W[d * 300 + h * kCC + c] * att_dst[h * kCC + c];
      ws_dst[j] = s;
    } else {
      int j = i - 2400;
      bias_sum[j] = b_ih[j] + b_hh[j];
    }
  }
}

// ---------------- prep: bf16 input-transform weights ------------------------
__global__ void wx_prep(const float* __restrict__ W_ih0,
                        const float* __restrict__ W_ih_rest,
                        u16* __restrict__ wx0, u16* __restrict__ wx12) {
  const int n0 = 4096 * 640;
  const int n12 = 2 * 4096 * 1024;
  int total = n0 + n12;
  for (int i = blockIdx.x * blockDim.x + threadIdx.x; i < total; i += gridDim.x * blockDim.x) {
    if (i < n0) {
      int row = i / 640, col = i - row * 640;
      float v = (col < 600) ? W_ih0[row * 600 + col] : 0.f;
      wx0[i] = f2bf(v);
    } else {
      int j = i - n0;
      wx12[j] = f2bf(W_ih_rest[j]);
    }
  }
}

// ---------------- prep: bf16 copy of lin_W (halves GEMM B traffic) ----------
__global__ void wb_conv(const float* __restrict__ W, u16* __restrict__ Wb) {
  const long n = (long)kVG * 1024;
  long stride = (long)gridDim.x * blockDim.x * 8;
  for (long i = (long)(blockIdx.x * blockDim.x + threadIdx.x) * 8; i < n; i += stride) {
    float4 a = *(const float4*)(W + i);
    float4 b = *(const float4*)(W + i + 4);
    u16 t[8] = {f2bf(a.x), f2bf(a.y), f2bf(a.z), f2bf(a.w),
                f2bf(b.x), f2bf(b.y), f2bf(b.z), f2bf(b.w)};
    *(uint4*)(Wb + i) = *(const uint4*)t;
  }
}

// ---------------- GAT (node-0 only, factored attention) ---------------------
__global__ void __launch_bounds__(256) gat_kernel(
    const int* __restrict__ x_indices, const int* __restrict__ edge_index,
    const float* __restrict__ X, const float* __restrict__ gat_W,
    const float* __restrict__ gat_bias, const float* __restrict__ ws_src,
    const float* __restrict__ ws_dst, u16* __restrict__ sig) {
  __shared__ float xs[32][301];
  __shared__ float a_s[32][4];
  __shared__ float a_d0[4];
  __shared__ float alpha[4][32];
  __shared__ float xw[4][301];
  __shared__ int allowed[32];
  int g = blockIdx.x, tid = threadIdx.x;
  const int* idx = x_indices + g * 32;
  for (int i = tid; i < 32 * 300; i += 256) {
    int j = i / 300, d2 = i - j * 300;
    xs[j][d2] = X[(size_t)idx[j] * 300 + d2];
  }
  if (tid < 32) allowed[tid] = (tid == 0) ? 1 : 0;
  __syncthreads();
  if (tid < 128) {
    int j = tid >> 2, h = tid & 3;
    float s = 0.f;
    for (int d2 = 0; d2 < 300; ++d2) s += xs[j][d2] * ws_src[d2 * 4 + h];
    a_s[j][h] = s;
  } else if (tid < 132) {
    int h = tid - 128; float s = 0.f;
    for (int d2 = 0; d2 < 300; ++d2) s += xs[0][d2] * ws_dst[d2 * 4 + h];
    a_d0[h] = s;
  } else if (tid >= 192) {
    int e = tid - 192;
    int src = edge_index[g * 128 + e];
    int dst = edge_index[g * 128 + 64 + e];
    if (dst == 0) allowed[src] = 1;
  }
  __syncthreads();
  if (tid < 4) {
    int h = tid;
    float ev[32];
    float mx = -1e30f;
    #pragma unroll
    for (int j = 0; j < 32; ++j) {
      float v = a_d0[h] + a_s[j][h];
      v = (v > 0.f) ? v : 0.2f * v;
      v = allowed[j] ? v : -1e9f;
      ev[j] = v; mx = fmaxf(mx, v);
    }
    float ssum = 0.f;
    #pragma unroll
    for (int j = 0; j < 32; ++j) { float p = fexp(ev[j] - mx); ev[j] = p; ssum += p; }
    float inv = 1.f / ssum;
    #pragma unroll
    for (int j = 0; j < 32; ++j) alpha[h][j] = ev[j] * inv;
  }
  __syncthreads();
  for (int i = tid; i < 4 * 300; i += 256) {
    int h = i / 300, d2 = i - h * 300;
    float s = 0.f;
    #pragma unroll
    for (int j = 0; j < 32; ++j) s += alpha[h][j] * xs[j][d2];
    xw[h][d2] = s;
  }
  __syncthreads();
  int t = g % 35, b = g / 35;
  u16* srow = sig + ((size_t)t * 32 + b) * 640;
  for (int hc = tid; hc < 300; hc += 256) {
    srow[hc] = f2bf(xs[0][hc]);           // curr_emb = X[idx 0]
    int h = hc / 75;
    float s = gat_bias[hc];
    for (int d2 = 0; d2 < 300; ++d2) s += xw[h][d2] * gat_W[d2 * 300 + hc];
    srow[300 + hc] = f2bf(s);
  }
  for (int i2 = 600 + tid; i2 < 640; i2 += 256) srow[i2] = 0;  // zero pad
}

// ---------------- contention-free flag barrier ------------------------------
// Each block stores a monotonically increasing step number into its OWN slot
// (no same-line RMW serialization); wave 0 of every block polls all slots.
DEV void flag_barrier(unsigned* flags, int nb, unsigned s) {
  __syncthreads();
  if (threadIdx.x == 0) {
    __threadfence();   // release our h stores once
    __hip_atomic_store(flags + blockIdx.x, s, __ATOMIC_RELAXED, __HIP_MEMORY_SCOPE_AGENT);
  }
  if (threadIdx.x < 64) {
    for (int j = threadIdx.x; j < nb; j += 64) {
      while (__hip_atomic_load(flags + j, __ATOMIC_RELAXED, __HIP_MEMORY_SCOPE_AGENT) < s)
        __builtin_amdgcn_s_sleep(1);
    }
    if (threadIdx.x == 0) __threadfence();  // acquire (invalidate L1) once
  }
  __syncthreads();
}

// ---------------- bulk input-gate GEMM: gates[m][4096] = A[m][K] @ Bw[4096][K]^T
__global__ void __launch_bounds__(256, 1) gemm_ig(
    const u16* __restrict__ A, const u16* __restrict__ Bw,
    float* __restrict__ gates, int K) {
  int bid = blockIdx.x;
  int bm = bid % 9, bn = bid / 9;
  int m0 = bm * 128, n0 = bn * 128;
  int tid = threadIdx.x, w = tid >> 6, lane = tid & 63, l15 = lane & 15, lhi = lane >> 4;
  int wm = w & 1, wn = w >> 1;
  __shared__ u16 As[128][40];
  __shared__ u16 Bs[128][40];
  f32x4 acc[4][4];
  #pragma unroll
  for (int i = 0; i < 4; ++i)
    #pragma unroll
    for (int j = 0; j < 4; ++j) { f32x4 z = {0.f, 0.f, 0.f, 0.f}; acc[i][j] = z; }

  int nkt = K >> 5;
  for (int kt = 0; kt < nkt; ++kt) {
    int k0 = kt * 32;
    #pragma unroll
    for (int q = 0; q < 2; ++q) {
      int c = tid * 2 + q; int row = c >> 2; int ch = c & 3;
      int m = m0 + row;
      uint4 av{0u, 0u, 0u, 0u};
      if (m < kM) av = *(const uint4*)(A + (size_t)m * K + k0 + ch * 8);
      *(uint4*)&As[row][ch * 8] = av;
      int n = n0 + row;
      uint4 bv = *(const uint4*)(Bw + (size_t)n * K + k0 + ch * 8);
      *(uint4*)&Bs[row][ch * 8] = bv;
    }
    __syncthreads();
    short8 bfr[4];
    #pragma unroll
    for (int nt = 0; nt < 4; ++nt)
      bfr[nt] = *(const short8*)&Bs[wn * 64 + nt * 16 + l15][lhi * 8];
    #pragma unroll
    for (int mt = 0; mt < 4; ++mt) {
      short8 af = *(const short8*)&As[wm * 64 + mt * 16 + l15][lhi * 8];
      #pragma unroll
      for (int nt = 0; nt < 4; ++nt)
        acc[mt][nt] = mfma16(af, bfr[nt], acc[mt][nt]);
    }
    __syncthreads();
  }
  #pragma unroll
  for (int mt = 0; mt < 4; ++mt) {
    #pragma unroll
    for (int r = 0; r < 4; ++r) {
      int m = m0 + wm * 64 + mt * 16 + lhi * 4 + r;
      if (m < kM) {
        float* orow = gates + (size_t)m * 4096;
        #pragma unroll
        for (int nt = 0; nt < 4; ++nt) {
          int n = n0 + wn * 64 + nt * 16 + l15;
          orow[n] = acc[mt][nt][r];
        }
      }
    }
  }
}

// ---------------- LSTM recurrence: one layer, W_hh LDS-resident -------------
// 128 blocks, block p owns units [8p, 8p+8). 34 flag barriers.
__global__ void __launch_bounds__(256, 1) lstm_rec(
    const float* __restrict__ W_hh_l,   // [4096][1024] fp32, this layer
    const float* __restrict__ gates,    // [1120][4096] f32 (x-part, precomputed)
    const float* __restrict__ bias_l,   // [4096]
    u16* __restrict__ hout,             // [35*32][1024] bf16
    unsigned* flags, unsigned sbase) {
  const int p = blockIdx.x;
  const int tid = threadIdx.x;
  const int w = tid >> 6, lane = tid & 63, l15 = lane & 15, lhi = lane >> 4;
  __shared__ u16 whs[32][1032];         // rows: idx = g*8+jj -> global g*1024+8p+jj
  __shared__ float pred[4][32][33];     // [wave][w-row][batch]
  for (int i = tid; i < 32 * 256; i += 256) {
    int row = i >> 8, seg = i & 255;
    int g = row >> 3, jj = row & 7;
    const float* src = W_hh_l + ((size_t)(g * 1024 + p * 8 + jj)) * 1024 + seg * 4;
    float4 f = *(const float4*)src;
    u16 tmp[4] = {f2bf(f.x), f2bf(f.y), f2bf(f.z), f2bf(f.w)};
    *(uint2*)&whs[row][seg * 4] = *(const uint2*)tmp;
  }
  const int bb = tid >> 3, jj2 = tid & 7;
  float bias_r[4];
  #pragma unroll
  for (int g = 0; g < 4; ++g) bias_r[g] = bias_l[g * 1024 + p * 8 + jj2];
  float c_reg = 0.f;
  const int kbase = w * 256;
  const float* gbase = gates + p * 8 + jj2 + (size_t)bb * 4096;

  // prefetch gx for t=0
  float gx[4];
  #pragma unroll
  for (int g = 0; g < 4; ++g) gx[g] = gbase[g * 1024];

  for (int t = 0; t < 35; ++t) {
    float gxn[4];
    if (t > 0) {
      const u16* hp = hout + (size_t)(t - 1) * 32 * 1024;
      const u16* hrow0 = hp + l15 * 1024 + lhi * 8;
      const u16* hrow1 = hp + (l15 + 16) * 1024 + lhi * 8;
      f32x4 acc00 = {0,0,0,0}, acc01 = {0,0,0,0}, acc10 = {0,0,0,0}, acc11 = {0,0,0,0};
      #pragma unroll
      for (int kk = 0; kk < 8; ++kk) {
        int k = kbase + kk * 32;
        short8 bf0 = *(const short8*)(hrow0 + k);
        short8 bf1 = *(const short8*)(hrow1 + k);
        short8 af0 = *(const short8*)&whs[l15][k + lhi * 8];
        short8 af1 = *(const short8*)&whs[16 + l15][k + lhi * 8];
        acc00 = mfma16(af0, bf0, acc00);
        acc01 = mfma16(af0, bf1, acc01);
        acc10 = mfma16(af1, bf0, acc10);
        acc11 = mfma16(af1, bf1, acc11);
      }
      // prefetch next step's gx while MFMAs drain (gates is constant data)
      if (t < 34) {
        const float* gp = gbase + (size_t)(t + 1) * 32 * 4096;
        #pragma unroll
        for (int g = 0; g < 4; ++g) gxn[g] = gp[g * 1024];
      }
      #pragma unroll
      for (int r = 0; r < 4; ++r) {
        pred[w][lhi * 4 + r][l15]       = acc00[r];
        pred[w][lhi * 4 + r][l15 + 16]  = acc01[r];
        pred[w][16 + lhi * 4 + r][l15]      = acc10[r];
        pred[w][16 + lhi * 4 + r][l15 + 16] = acc11[r];
      }
      __syncthreads();
    } else {
      const float* gp = gbase + (size_t)32 * 4096;
      #pragma unroll
      for (int g = 0; g < 4; ++g) gxn[g] = gp[g * 1024];
    }
    float pre[4];
    #pragma unroll
    for (int g = 0; g < 4; ++g) {
      float s = 0.f;
      if (t > 0) {
        int row = g * 8 + jj2;
        s = pred[0][row][bb] + pred[1][row][bb] + pred[2][row][bb] + pred[3][row][bb];
      }
      pre[g] = s;
    }
    float iv = gx[0] + pre[0] + bias_r[0];
    float fv = gx[1] + pre[1] + bias_r[1];
    float gv = gx[2] + pre[2] + bias_r[2];
    float ov = gx[3] + pre[3] + bias_r[3];
    float cc = fsigm(fv) * c_reg + fsigm(iv) * ftanh(gv);
    float hh = fsigm(ov) * ftanh(cc);
    c_reg = cc;
    hout[((size_t)(t * 32 + bb)) * 1024 + p * 8 + jj2] = f2bf(hh);
    if (t < 34) flag_barrier(flags, 128, sbase + (unsigned)t + 1u);
    #pragma unroll
    for (int g = 0; g < 4; ++g) gx[g] = gxn[g];
  }
}

// ---------------- logits GEMM (1120x50000x1024, bf16 MFMA) + row partials ---
template <bool BW16>
__global__ void __launch_bounds__(256, 1) gemm_logits(
    const u16* __restrict__ hist2, const u16* __restrict__ linwb,
    const float* __restrict__ lin_W, const float* __restrict__ lin_b,
    float* __restrict__ out, float2* __restrict__ partials) {
  // XCD-bijective swizzle: 9 consecutive logical tiles (one B-strip) -> one XCD
  int nwg = gridDim.x, orig = blockIdx.x;
  int q = nwg >> 3, r = nwg & 7, xcd = orig & 7, off = orig >> 3;
  int bid = (xcd < r ? xcd * (q + 1) : r * (q + 1) + (xcd - r) * q) + off;
  int bm = bid % 9, bn = bid / 9;
  int m0 = bm * 128, n0 = bn * 128;
  int tid = threadIdx.x, w = tid >> 6, lane = tid & 63, l15 = lane & 15, lhi = lane >> 4;
  int wm = w & 1, wn = w >> 1;
  __shared__ u16 As[128][48];
  __shared__ u16 Bs[128][48];
  f32x4 acc[4][4];
  #pragma unroll
  for (int i = 0; i < 4; ++i)
    #pragma unroll
    for (int j = 0; j < 4; ++j) { f32x4 z = {0.f, 0.f, 0.f, 0.f}; acc[i][j] = z; }

  for (int kt = 0; kt < 32; ++kt) {
    int k0 = kt * 32;
    #pragma unroll
    for (int q2 = 0; q2 < 2; ++q2) {
      int c = tid * 2 + q2; int row = c >> 2; int ch = c & 3;
      int m = m0 + row;
      uint4 av{0u, 0u, 0u, 0u};
      if (m < kM) {
        int b = m / 35; int t = m - b * 35;
        av = *(const uint4*)(hist2 + ((size_t)(t * 32 + b) << 10) + k0 + ch * 8);
      }
      *(uint4*)&As[row][ch * 8] = av;
      int n = n0 + row;
      uint4 bv{0u, 0u, 0u, 0u};
      if (n < kVG) {
        if (BW16) {
          bv = *(const uint4*)(linwb + (size_t)n * 1024 + k0 + ch * 8);
        } else {
          const float* src = lin_W + (size_t)n * 1024 + k0 + ch * 8;
          float4 f0 = *(const float4*)(src);
          float4 f1 = *(const float4*)(src + 4);
          bv.x = (unsigned)f2bf(f0.x) | ((unsigned)f2bf(f0.y) << 16);
          bv.y = (unsigned)f2bf(f0.z) | ((unsigned)f2bf(f0.w) << 16);
          bv.z = (unsigned)f2bf(f1.x) | ((unsigned)f2bf(f1.y) << 16);
          bv.w = (unsigned)f2bf(f1.z) | ((unsigned)f2bf(f1.w) << 16);
        }
      }
      *(uint4*)&Bs[row][ch * 8] = bv;
    }
    __syncthreads();
    short8 bfr[4];
    #pragma unroll
    for (int nt = 0; nt < 4; ++nt)
      bfr[nt] = *(const short8*)&Bs[wn * 64 + nt * 16 + l15][lhi * 8];
    #pragma unroll
    for (int mt = 0; mt < 4; ++mt) {
      short8 af = *(const short8*)&As[wm * 64 + mt * 16 + l15][lhi * 8];
      #pragma unroll
      for (int nt = 0; nt < 4; ++nt)
        acc[mt][nt] = mfma16(af, bfr[nt], acc[mt][nt]);
    }
    __syncthreads();
  }
  // epilogue: store logits + per-(row, 64-col-group) max/sumexp partials
  float bcol[4]; int ncol[4];
  #pragma unroll
  for (int nt = 0; nt < 4; ++nt) {
    int n = n0 + wn * 64 + nt * 16 + l15;
    ncol[nt] = n;
    bcol[nt] = (n < kVG) ? lin_b[n] : -INFINITY;
  }
  #pragma unroll
  for (int mt = 0; mt < 4; ++mt) {
    #pragma unroll
    for (int r = 0; r < 4; ++r) {
      int m = m0 + wm * 64 + mt * 16 + lhi * 4 + r;
      float v0 = acc[mt][0][r] + bcol[0];
      float v1 = acc[mt][1][r] + bcol[1];
      float v2 = acc[mt][2][r] + bcol[2];
      float v3 = acc[mt][3][r] + bcol[3];
      bool mok = (m < kM);
      if (mok) {
        float* orow = out + (size_t)m * kVG;
        if (ncol[0] < kVG) orow[ncol[0]] = v0;
        if (ncol[1] < kVG) orow[ncol[1]] = v1;
        if (ncol[2] < kVG) orow[ncol[2]] = v2;
        if (ncol[3] < kVG) orow[ncol[3]] = v3;
      }
      float mx = fmaxf(fmaxf(v0, v1), fmaxf(v2, v3));
      #pragma unroll
      for (int d2 = 1; d2 < 16; d2 <<= 1) mx = fmaxf(mx, __shfl_xor(mx, d2, 64));
      float sv = 0.f;
      sv += (v0 > -1e30f) ? fexp(v0 - mx) : 0.f;
      sv += (v1 > -1e30f) ? fexp(v1 - mx) : 0.f;
      sv += (v2 > -1e30f) ? fexp(v2 - mx) : 0.f;
      sv += (v3 > -1e30f) ? fexp(v3 - mx) : 0.f;
      #pragma unroll
      for (int d2 = 1; d2 < 16; d2 <<= 1) sv += __shfl_xor(sv, d2, 64);
      if (mok && l15 == 0)
        partials[(size_t)m * 784 + bn * 2 + wn] = make_float2(mx, sv);
    }
  }
}

// ---------------- row logsumexp reduce --------------------------------------
__global__ void reduce_rows(const float2* __restrict__ partials, float* __restrict__ lse) {
  int m = blockIdx.x, tid = threadIdx.x;
  float mx = -INFINITY, s = 0.f;
  for (int j = tid; j < 782; j += 256) {
    float2 p = partials[(size_t)m * 784 + j];
    if (p.x > mx) { s = s * fexp(mx - p.x) + p.y; mx = p.x; }
    else          { s += p.y * fexp(p.x - mx); }
  }
  for (int d = 1; d < 64; d <<= 1) {
    float omx = __shfl_xor(mx, d, 64);
    float os  = __shfl_xor(s, d, 64);
    if (omx > mx) { s = s * fexp(mx - omx) + os; mx = omx; }
    else          { s += os * fexp(omx - mx); }
  }
  __shared__ float smx[4], ssum[4];
  int w = tid >> 6;
  if ((tid & 63) == 0) { smx[w] = mx; ssum[w] = s; }
  __syncthreads();
  if (tid == 0) {
    for (int i = 1; i < 4; ++i) {
      float omx = smx[i], os = ssum[i];
      if (omx > mx) { s = s * fexp(mx - omx) + os; mx = omx; }
      else          { s += os * fexp(omx - mx); }
    }
    lse[m] = mx + logf(s);
  }
}

// ---------------- in-place log_softmax subtract -----------------------------
__global__ void sub_lse(float* __restrict__ out, const float* __restrict__ lse) {
  const int total4 = 14000000;  // 1120*50000/4
  for (int i = blockIdx.x * blockDim.x + threadIdx.x; i < total4; i += gridDim.x * blockDim.x) {
    int m = i / 12500;
    float4 v = ((float4*)out)[i];
    float L = lse[m];
    v.x -= L; v.y -= L; v.z -= L; v.w -= L;
    ((float4*)out)[i] = v;
  }
}

// ---------------- launch ----------------------------------------------------
extern "C" void kernel_launch(void* const* d_in, const int* in_sizes, int n_in,
                              void* d_out, int out_size, void* d_ws, size_t ws_size,
                              hipStream_t stream) {
  const int*   x_indices  = (const int*)d_in[0];
  const int*   edge_index = (const int*)d_in[1];
  const float* X          = (const float*)d_in[2];
  const float* gat_W      = (const float*)d_in[3];
  const float* att_src    = (const float*)d_in[4];
  const float* att_dst    = (const float*)d_in[5];
  const float* gat_bias   = (const float*)d_in[6];
  const float* W_ih0      = (const float*)d_in[7];
  const float* W_ih_rest  = (const float*)d_in[8];
  const float* W_hh       = (const float*)d_in[9];
  const float* b_ih       = (const float*)d_in[10];
  const float* b_hh       = (const float*)d_in[11];
  const float* lin_W      = (const float*)d_in[12];
  const float* lin_b      = (const float*)d_in[13];
  float* out = (float*)d_out;
  char* ws = (char*)d_ws;

  unsigned* flags    = (unsigned*)(ws + OFF_BAR);
  float*    ws_src   = (float*)(ws + OFF_WSRC);
  float*    ws_dst   = (float*)(ws + OFF_WDST);
  float*    bias_sum = (float*)(ws + OFF_BIAS);
  u16*      sig      = (u16*)(ws + OFF_SIG);
  u16*      wx0      = (u16*)(ws + OFF_WX0);
  u16*      wx12     = (u16*)(ws + OFF_WX12);
  float*    gates    = (float*)(ws + OFF_GATES);
  u16*      hist     = (u16*)(ws + OFF_HIST);
  float2*   partials = (float2*)(ws + OFF_PART);
  float*    lse      = (float*)(ws + OFF_LSE);
  u16*      linwb    = (u16*)(ws + OFF_LINWB);
  bool use_bw = (ws_size >= kNeedBW);

  u16* hist0 = hist;
  u16* hist1 = hist + (size_t)35 * 32 * 1024;
  u16* hist2 = hist + (size_t)2 * 35 * 32 * 1024;

  hipMemsetAsync(ws + OFF_BAR, 0, 1024, stream);
  prep_small<<<64, 256, 0, stream>>>(gat_W, att_src, att_dst, b_ih, b_hh,
                                     ws_src, ws_dst, bias_sum);
  wx_prep<<<1024, 256, 0, stream>>>(W_ih0, W_ih_rest, wx0, wx12);
  if (use_bw) wb_conv<<<2048, 256, 0, stream>>>(lin_W, linwb);
  gat_kernel<<<kG, 256, 0, stream>>>(x_indices, edge_index, X, gat_W, gat_bias,
                                     ws_src, ws_dst, sig);
  // layer 0
  gemm_ig<<<288, 256, 0, stream>>>(sig, wx0, gates, 640);
  lstm_rec<<<128, 256, 0, stream>>>(W_hh, gates, bias_sum, hist0, flags, 0u);
  // layer 1
  gemm_ig<<<288, 256, 0, stream>>>(hist0, wx12, gates, 1024);
  lstm_rec<<<128, 256, 0, stream>>>(W_hh + (size_t)4096 * 1024, gates,
                                    bias_sum + 4096, hist1, flags, 34u);
  // layer 2
  gemm_ig<<<288, 256, 0, stream>>>(hist1, wx12 + (size_t)4096 * 1024, gates, 1024);
  lstm_rec<<<128, 256, 0, stream>>>(W_hh + (size_t)2 * 4096 * 1024, gates,
                                    bias_sum + 8192, hist2, flags, 68u);
  // logits + log_softmax
  if (use_bw)
    gemm_logits<true><<<9 * 391, 256, 0, stream>>>(hist2, linwb, lin_W, lin_b, out, partials);
  else
    gemm_logits<false><<<9 * 391, 256, 0, stream>>>(hist2, nullptr, lin_W, lin_b, out, partials);
  reduce_rows<<<kG, 256, 0, stream>>>(partials, lse);
  sub_lse<<<2048, 256, 0, stream>>>(out, lse);
}

// Round 6
// 1256.296 us; speedup vs baseline: 2.0771x; 1.4688x over previous
//
#include <hip/hip_runtime.h>

#define DEV __device__ __forceinline__

typedef __attribute__((ext_vector_type(8))) short short8;
typedef __attribute__((ext_vector_type(4))) float f32x4;
typedef unsigned short u16;

constexpr int kV = 80000, kD = 300, kNN = 32, kEE = 64, kHH = 4, kCC = 75;
constexpr int kB = 32, kT = 35, kU = 1024, kVG = 50000;
constexpr int kG = kB * kT;          // 1120
constexpr int kM = kG;

constexpr size_t alignup(size_t x) { return (x + 255) & ~size_t(255); }
constexpr size_t OFF_BAR   = 0;       // 128 flag slots (1024 B reserved)
constexpr size_t OFF_WSRC  = 1024;
constexpr size_t OFF_WDST  = alignup(OFF_WSRC + 1200 * 4);
constexpr size_t OFF_BIAS  = alignup(OFF_WDST + 1200 * 4);
constexpr size_t OFF_SIG   = alignup(OFF_BIAS + 3 * 4096 * 4);
constexpr size_t OFF_WX0   = alignup(OFF_SIG + (size_t)35 * 32 * 640 * 2);
constexpr size_t OFF_WX12  = alignup(OFF_WX0 + (size_t)4096 * 640 * 2);
constexpr size_t OFF_GATES = alignup(OFF_WX12 + (size_t)2 * 4096 * 1024 * 2);
constexpr size_t OFF_HIST  = alignup(OFF_GATES + (size_t)1120 * 4096 * 4);
constexpr size_t OFF_PART  = alignup(OFF_HIST + (size_t)3 * 35 * 32 * 1024 * 2);
constexpr size_t OFF_LSE   = alignup(OFF_PART + (size_t)1120 * 784 * 8);
constexpr size_t OFF_LINWB = alignup(OFF_LSE + 1120 * 4);
constexpr size_t kLinWBytes = (size_t)kVG * 1024 * 2;
constexpr size_t kNeedBW   = OFF_LINWB + kLinWBytes;

DEV u16 f2bf(float f) {
  union { float f; unsigned u; } v; v.f = f;
  unsigned r = v.u + 0x7fffu + ((v.u >> 16) & 1u);
  return (u16)(r >> 16);
}
// fast transcendentals via v_exp_f32 (2^x) + v_rcp_f32; abs tolerance is ~0.2
DEV float fexp(float x) { return __builtin_amdgcn_exp2f(x * 1.4426950408889634f); }
DEV float fsigm(float x) {
  float t = __builtin_amdgcn_exp2f(-1.4426950408889634f * x);
  return __builtin_amdgcn_rcpf(1.f + t);
}
DEV float ftanh(float x) {
  float xc = fminf(fmaxf(x, -20.f), 20.f);
  float t = __builtin_amdgcn_exp2f(2.8853900817779268f * xc);
  return (t - 1.f) * __builtin_amdgcn_rcpf(t + 1.f);
}
DEV f32x4 mfma16(short8 a, short8 b, f32x4 c) {
  return __builtin_amdgcn_mfma_f32_16x16x32_bf16(a, b, c, 0, 0, 0);
}
// store a bf16 directly to the coherent LLC (bypass non-coherent per-XCD L2).
// This keeps L2 free of dirty h lines -> no buffer_wbl2/buffer_inv fences
// needed for cross-XCD visibility; __syncthreads' vmcnt(0) drain suffices.
DEV void store_u16_llc(u16* p, u16 v) {
  unsigned vv = v;
  asm volatile("global_store_short %0, %1, off sc0 sc1"
               :: "v"(p), "v"(vv) : "memory");
}

// ---------------- prep: ws_src/ws_dst (W @ att vectors), bias sums ----------
__global__ void prep_small(const float* __restrict__ gat_W,
                           const float* __restrict__ att_src,
                           const float* __restrict__ att_dst,
                           const float* __restrict__ b_ih,
                           const float* __restrict__ b_hh,
                           float* __restrict__ ws_src, float* __restrict__ ws_dst,
                           float* __restrict__ bias_sum) {
  int total = 1200 + 1200 + 3 * 4096;
  for (int i = blockIdx.x * blockDim.x + threadIdx.x; i < total; i += gridDim.x * blockDim.x) {
    if (i < 1200) {
      int d = i >> 2, h = i & 3;
      float s = 0.f;
      for (int c = 0; c < kCC; ++c) s += gat_W[d * 300 + h * kCC + c] * att_src[h * kCC + c];
      ws_src[i] = s;
    } else if (i < 2400) {
      int j = i - 1200; int d = j >> 2, h = j & 3;
      float s = 0.f;
      for (int c = 0; c < kCC; ++c) s += gat_W[d * 300 + h * kCC + c] * att_dst[h * kCC + c];
      ws_dst[j] = s;
    } else {
      int j = i - 2400;
      bias_sum[j] = b_ih[j] + b_hh[j];
    }
  }
}

// ---------------- prep: bf16 input-transform weights ------------------------
__global__ void wx_prep(const float* __restrict__ W_ih0,
                        const float* __restrict__ W_ih_rest,
                        u16* __restrict__ wx0, u16* __restrict__ wx12) {
  const int n0 = 4096 * 640;
  const int n12 = 2 * 4096 * 1024;
  int total = n0 + n12;
  for (int i = blockIdx.x * blockDim.x + threadIdx.x; i < total; i += gridDim.x * blockDim.x) {
    if (i < n0) {
      int row = i / 640, col = i - row * 640;
      float v = (col < 600) ? W_ih0[row * 600 + col] : 0.f;
      wx0[i] = f2bf(v);
    } else {
      int j = i - n0;
      wx12[j] = f2bf(W_ih_rest[j]);
    }
  }
}

// ---------------- prep: bf16 copy of lin_W (halves GEMM B traffic) ----------
__global__ void wb_conv(const float* __restrict__ W, u16* __restrict__ Wb) {
  const long n = (long)kVG * 1024;
  long stride = (long)gridDim.x * blockDim.x * 8;
  for (long i = (long)(blockIdx.x * blockDim.x + threadIdx.x) * 8; i < n; i += stride) {
    float4 a = *(const float4*)(W + i);
    float4 b = *(const float4*)(W + i + 4);
    u16 t[8] = {f2bf(a.x), f2bf(a.y), f2bf(a.z), f2bf(a.w),
                f2bf(b.x), f2bf(b.y), f2bf(b.z), f2bf(b.w)};
    *(uint4*)(Wb + i) = *(const uint4*)t;
  }
}

// ---------------- GAT (node-0 only, factored attention) ---------------------
__global__ void __launch_bounds__(256) gat_kernel(
    const int* __restrict__ x_indices, const int* __restrict__ edge_index,
    const float* __restrict__ X, const float* __restrict__ gat_W,
    const float* __restrict__ gat_bias, const float* __restrict__ ws_src,
    const float* __restrict__ ws_dst, u16* __restrict__ sig) {
  __shared__ float xs[32][301];
  __shared__ float a_s[32][4];
  __shared__ float a_d0[4];
  __shared__ float alpha[4][32];
  __shared__ float xw[4][301];
  __shared__ int allowed[32];
  int g = blockIdx.x, tid = threadIdx.x;
  const int* idx = x_indices + g * 32;
  for (int i = tid; i < 32 * 300; i += 256) {
    int j = i / 300, d2 = i - j * 300;
    xs[j][d2] = X[(size_t)idx[j] * 300 + d2];
  }
  if (tid < 32) allowed[tid] = (tid == 0) ? 1 : 0;
  __syncthreads();
  if (tid < 128) {
    int j = tid >> 2, h = tid & 3;
    float s = 0.f;
    for (int d2 = 0; d2 < 300; ++d2) s += xs[j][d2] * ws_src[d2 * 4 + h];
    a_s[j][h] = s;
  } else if (tid < 132) {
    int h = tid - 128; float s = 0.f;
    for (int d2 = 0; d2 < 300; ++d2) s += xs[0][d2] * ws_dst[d2 * 4 + h];
    a_d0[h] = s;
  } else if (tid >= 192) {
    int e = tid - 192;
    int src = edge_index[g * 128 + e];
    int dst = edge_index[g * 128 + 64 + e];
    if (dst == 0) allowed[src] = 1;
  }
  __syncthreads();
  if (tid < 4) {
    int h = tid;
    float ev[32];
    float mx = -1e30f;
    #pragma unroll
    for (int j = 0; j < 32; ++j) {
      float v = a_d0[h] + a_s[j][h];
      v = (v > 0.f) ? v : 0.2f * v;
      v = allowed[j] ? v : -1e9f;
      ev[j] = v; mx = fmaxf(mx, v);
    }
    float ssum = 0.f;
    #pragma unroll
    for (int j = 0; j < 32; ++j) { float p = fexp(ev[j] - mx); ev[j] = p; ssum += p; }
    float inv = 1.f / ssum;
    #pragma unroll
    for (int j = 0; j < 32; ++j) alpha[h][j] = ev[j] * inv;
  }
  __syncthreads();
  for (int i = tid; i < 4 * 300; i += 256) {
    int h = i / 300, d2 = i - h * 300;
    float s = 0.f;
    #pragma unroll
    for (int j = 0; j < 32; ++j) s += alpha[h][j] * xs[j][d2];
    xw[h][d2] = s;
  }
  __syncthreads();
  int t = g % 35, b = g / 35;
  u16* srow = sig + ((size_t)t * 32 + b) * 640;
  for (int hc = tid; hc < 300; hc += 256) {
    srow[hc] = f2bf(xs[0][hc]);           // curr_emb = X[idx 0]
    int h = hc / 75;
    float s = gat_bias[hc];
    for (int d2 = 0; d2 < 300; ++d2) s += xw[h][d2] * gat_W[d2 * 300 + hc];
    srow[300 + hc] = f2bf(s);
  }
  for (int i2 = 600 + tid; i2 < 640; i2 += 256) srow[i2] = 0;  // zero pad
}

// ---------------- fence-free flag barrier -----------------------------------
// Preconditions: all cross-block data is stored via sc0|sc1 (LLC-direct), so
// no L2 writeback/invalidate is needed. __syncthreads() drains vmcnt (stores
// complete at LLC) before the flag store; readers' data loads are first-touch.
DEV void flag_barrier(unsigned* flags, int nb, unsigned s) {
  __syncthreads();   // implies s_waitcnt vmcnt(0): h stores are at LLC
  if (threadIdx.x == 0)
    __hip_atomic_store(flags + blockIdx.x, s, __ATOMIC_RELAXED, __HIP_MEMORY_SCOPE_AGENT);
  if (threadIdx.x < 64) {
    for (int j = threadIdx.x; j < nb; j += 64) {
      while (__hip_atomic_load(flags + j, __ATOMIC_RELAXED, __HIP_MEMORY_SCOPE_AGENT) < s)
        __builtin_amdgcn_s_sleep(1);
    }
  }
  __syncthreads();   // codegen + execution barrier: no h load hoists above
}

// ---------------- bulk input-gate GEMM: gates[m][4096] = A[m][K] @ Bw[4096][K]^T
__global__ void __launch_bounds__(256, 1) gemm_ig(
    const u16* __restrict__ A, const u16* __restrict__ Bw,
    float* __restrict__ gates, int K) {
  int bid = blockIdx.x;
  int bm = bid % 9, bn = bid / 9;
  int m0 = bm * 128, n0 = bn * 128;
  int tid = threadIdx.x, w = tid >> 6, lane = tid & 63, l15 = lane & 15, lhi = lane >> 4;
  int wm = w & 1, wn = w >> 1;
  __shared__ u16 As[128][40];
  __shared__ u16 Bs[128][40];
  f32x4 acc[4][4];
  #pragma unroll
  for (int i = 0; i < 4; ++i)
    #pragma unroll
    for (int j = 0; j < 4; ++j) { f32x4 z = {0.f, 0.f, 0.f, 0.f}; acc[i][j] = z; }

  int nkt = K >> 5;
  for (int kt = 0; kt < nkt; ++kt) {
    int k0 = kt * 32;
    #pragma unroll
    for (int q = 0; q < 2; ++q) {
      int c = tid * 2 + q; int row = c >> 2; int ch = c & 3;
      int m = m0 + row;
      uint4 av{0u, 0u, 0u, 0u};
      if (m < kM) av = *(const uint4*)(A + (size_t)m * K + k0 + ch * 8);
      *(uint4*)&As[row][ch * 8] = av;
      int n = n0 + row;
      uint4 bv = *(const uint4*)(Bw + (size_t)n * K + k0 + ch * 8);
      *(uint4*)&Bs[row][ch * 8] = bv;
    }
    __syncthreads();
    short8 bfr[4];
    #pragma unroll
    for (int nt = 0; nt < 4; ++nt)
      bfr[nt] = *(const short8*)&Bs[wn * 64 + nt * 16 + l15][lhi * 8];
    #pragma unroll
    for (int mt = 0; mt < 4; ++mt) {
      short8 af = *(const short8*)&As[wm * 64 + mt * 16 + l15][lhi * 8];
      #pragma unroll
      for (int nt = 0; nt < 4; ++nt)
        acc[mt][nt] = mfma16(af, bfr[nt], acc[mt][nt]);
    }
    __syncthreads();
  }
  #pragma unroll
  for (int mt = 0; mt < 4; ++mt) {
    #pragma unroll
    for (int r = 0; r < 4; ++r) {
      int m = m0 + wm * 64 + mt * 16 + lhi * 4 + r;
      if (m < kM) {
        float* orow = gates + (size_t)m * 4096;
        #pragma unroll
        for (int nt = 0; nt < 4; ++nt) {
          int n = n0 + wn * 64 + nt * 16 + l15;
          orow[n] = acc[mt][nt][r];
        }
      }
    }
  }
}

// ---------------- LSTM recurrence: one layer, W_hh LDS-resident -------------
// 128 blocks, block p owns units [8p, 8p+8). 34 flag barriers, fence-free.
__global__ void __launch_bounds__(256, 1) lstm_rec(
    const float* __restrict__ W_hh_l,   // [4096][1024] fp32, this layer
    const float* __restrict__ gates,    // [1120][4096] f32 (x-part, precomputed)
    const float* __restrict__ bias_l,   // [4096]
    u16* __restrict__ hout,             // [35*32][1024] bf16
    unsigned* flags, unsigned sbase) {
  const int p = blockIdx.x;
  const int tid = threadIdx.x;
  const int w = tid >> 6, lane = tid & 63, l15 = lane & 15, lhi = lane >> 4;
  __shared__ u16 whs[32][1032];         // rows: idx = g*8+jj -> global g*1024+8p+jj
  __shared__ float pred[4][32][33];     // [wave][w-row][batch]
  for (int i = tid; i < 32 * 256; i += 256) {
    int row = i >> 8, seg = i & 255;
    int g = row >> 3, jj = row & 7;
    const float* src = W_hh_l + ((size_t)(g * 1024 + p * 8 + jj)) * 1024 + seg * 4;
    float4 f = *(const float4*)src;
    u16 tmp[4] = {f2bf(f.x), f2bf(f.y), f2bf(f.z), f2bf(f.w)};
    *(uint2*)&whs[row][seg * 4] = *(const uint2*)tmp;
  }
  const int bb = tid >> 3, jj2 = tid & 7;
  float bias_r[4];
  #pragma unroll
  for (int g = 0; g < 4; ++g) bias_r[g] = bias_l[g * 1024 + p * 8 + jj2];
  float c_reg = 0.f;
  const int kbase = w * 256;
  const float* gbase = gates + p * 8 + jj2 + (size_t)bb * 4096;

  // prefetch gx for t=0
  float gx[4];
  #pragma unroll
  for (int g = 0; g < 4; ++g) gx[g] = gbase[g * 1024];

  for (int t = 0; t < 35; ++t) {
    float gxn[4];
    if (t > 0) {
      const u16* hp = hout + (size_t)(t - 1) * 32 * 1024;
      const u16* hrow0 = hp + l15 * 1024 + lhi * 8;
      const u16* hrow1 = hp + (l15 + 16) * 1024 + lhi * 8;
      f32x4 acc00 = {0,0,0,0}, acc01 = {0,0,0,0}, acc10 = {0,0,0,0}, acc11 = {0,0,0,0};
      #pragma unroll
      for (int kk = 0; kk < 8; ++kk) {
        int k = kbase + kk * 32;
        short8 bf0 = *(const short8*)(hrow0 + k);
        short8 bf1 = *(const short8*)(hrow1 + k);
        short8 af0 = *(const short8*)&whs[l15][k + lhi * 8];
        short8 af1 = *(const short8*)&whs[16 + l15][k + lhi * 8];
        acc00 = mfma16(af0, bf0, acc00);
        acc01 = mfma16(af0, bf1, acc01);
        acc10 = mfma16(af1, bf0, acc10);
        acc11 = mfma16(af1, bf1, acc11);
      }
      // prefetch next step's gx while MFMAs drain (gates is constant data)
      if (t < 34) {
        const float* gp = gbase + (size_t)(t + 1) * 32 * 4096;
        #pragma unroll
        for (int g = 0; g < 4; ++g) gxn[g] = gp[g * 1024];
      }
      #pragma unroll
      for (int r = 0; r < 4; ++r) {
        pred[w][lhi * 4 + r][l15]       = acc00[r];
        pred[w][lhi * 4 + r][l15 + 16]  = acc01[r];
        pred[w][16 + lhi * 4 + r][l15]      = acc10[r];
        pred[w][16 + lhi * 4 + r][l15 + 16] = acc11[r];
      }
      __syncthreads();
    } else {
      const float* gp = gbase + (size_t)32 * 4096;
      #pragma unroll
      for (int g = 0; g < 4; ++g) gxn[g] = gp[g * 1024];
    }
    float pre[4];
    #pragma unroll
    for (int g = 0; g < 4; ++g) {
      float s = 0.f;
      if (t > 0) {
        int row = g * 8 + jj2;
        s = pred[0][row][bb] + pred[1][row][bb] + pred[2][row][bb] + pred[3][row][bb];
      }
      pre[g] = s;
    }
    float iv = gx[0] + pre[0] + bias_r[0];
    float fv = gx[1] + pre[1] + bias_r[1];
    float gv = gx[2] + pre[2] + bias_r[2];
    float ov = gx[3] + pre[3] + bias_r[3];
    float cc = fsigm(fv) * c_reg + fsigm(iv) * ftanh(gv);
    float hh = fsigm(ov) * ftanh(cc);
    c_reg = cc;
    store_u16_llc(hout + ((size_t)(t * 32 + bb)) * 1024 + p * 8 + jj2, f2bf(hh));
    if (t < 34) flag_barrier(flags, 128, sbase + (unsigned)t + 1u);
    #pragma unroll
    for (int g = 0; g < 4; ++g) gx[g] = gxn[g];
  }
}

// ---------------- logits GEMM (1120x50000x1024, bf16 MFMA) + row partials ---
template <bool BW16>
__global__ void __launch_bounds__(256, 1) gemm_logits(
    const u16* __restrict__ hist2, const u16* __restrict__ linwb,
    const float* __restrict__ lin_W, const float* __restrict__ lin_b,
    float* __restrict__ out, float2* __restrict__ partials) {
  // XCD-bijective swizzle: 9 consecutive logical tiles (one B-strip) -> one XCD
  int nwg = gridDim.x, orig = blockIdx.x;
  int q = nwg >> 3, r = nwg & 7, xcd = orig & 7, off = orig >> 3;
  int bid = (xcd < r ? xcd * (q + 1) : r * (q + 1) + (xcd - r) * q) + off;
  int bm = bid % 9, bn = bid / 9;
  int m0 = bm * 128, n0 = bn * 128;
  int tid = threadIdx.x, w = tid >> 6, lane = tid & 63, l15 = lane & 15, lhi = lane >> 4;
  int wm = w & 1, wn = w >> 1;
  __shared__ u16 As[128][48];
  __shared__ u16 Bs[128][48];
  f32x4 acc[4][4];
  #pragma unroll
  for (int i = 0; i < 4; ++i)
    #pragma unroll
    for (int j = 0; j < 4; ++j) { f32x4 z = {0.f, 0.f, 0.f, 0.f}; acc[i][j] = z; }

  for (int kt = 0; kt < 32; ++kt) {
    int k0 = kt * 32;
    #pragma unroll
    for (int q2 = 0; q2 < 2; ++q2) {
      int c = tid * 2 + q2; int row = c >> 2; int ch = c & 3;
      int m = m0 + row;
      uint4 av{0u, 0u, 0u, 0u};
      if (m < kM) {
        int b = m / 35; int t = m - b * 35;
        av = *(const uint4*)(hist2 + ((size_t)(t * 32 + b) << 10) + k0 + ch * 8);
      }
      *(uint4*)&As[row][ch * 8] = av;
      int n = n0 + row;
      uint4 bv{0u, 0u, 0u, 0u};
      if (n < kVG) {
        if (BW16) {
          bv = *(const uint4*)(linwb + (size_t)n * 1024 + k0 + ch * 8);
        } else {
          const float* src = lin_W + (size_t)n * 1024 + k0 + ch * 8;
          float4 f0 = *(const float4*)(src);
          float4 f1 = *(const float4*)(src + 4);
          bv.x = (unsigned)f2bf(f0.x) | ((unsigned)f2bf(f0.y) << 16);
          bv.y = (unsigned)f2bf(f0.z) | ((unsigned)f2bf(f0.w) << 16);
          bv.z = (unsigned)f2bf(f1.x) | ((unsigned)f2bf(f1.y) << 16);
          bv.w = (unsigned)f2bf(f1.z) | ((unsigned)f2bf(f1.w) << 16);
        }
      }
      *(uint4*)&Bs[row][ch * 8] = bv;
    }
    __syncthreads();
    short8 bfr[4];
    #pragma unroll
    for (int nt = 0; nt < 4; ++nt)
      bfr[nt] = *(const short8*)&Bs[wn * 64 + nt * 16 + l15][lhi * 8];
    #pragma unroll
    for (int mt = 0; mt < 4; ++mt) {
      short8 af = *(const short8*)&As[wm * 64 + mt * 16 + l15][lhi * 8];
      #pragma unroll
      for (int nt = 0; nt < 4; ++nt)
        acc[mt][nt] = mfma16(af, bfr[nt], acc[mt][nt]);
    }
    __syncthreads();
  }
  // epilogue: store logits + per-(row, 64-col-group) max/sumexp partials
  float bcol[4]; int ncol[4];
  #pragma unroll
  for (int nt = 0; nt < 4; ++nt) {
    int n = n0 + wn * 64 + nt * 16 + l15;
    ncol[nt] = n;
    bcol[nt] = (n < kVG) ? lin_b[n] : -INFINITY;
  }
  #pragma unroll
  for (int mt = 0; mt < 4; ++mt) {
    #pragma unroll
    for (int r = 0; r < 4; ++r) {
      int m = m0 + wm * 64 + mt * 16 + lhi * 4 + r;
      float v0 = acc[mt][0][r] + bcol[0];
      float v1 = acc[mt][1][r] + bcol[1];
      float v2 = acc[mt][2][r] + bcol[2];
      float v3 = acc[mt][3][r] + bcol[3];
      bool mok = (m < kM);
      if (mok) {
        float* orow = out + (size_t)m * kVG;
        if (ncol[0] < kVG) orow[ncol[0]] = v0;
        if (ncol[1] < kVG) orow[ncol[1]] = v1;
        if (ncol[2] < kVG) orow[ncol[2]] = v2;
        if (ncol[3] < kVG) orow[ncol[3]] = v3;
      }
      float mx = fmaxf(fmaxf(v0, v1), fmaxf(v2, v3));
      #pragma unroll
      for (int d2 = 1; d2 < 16; d2 <<= 1) mx = fmaxf(mx, __shfl_xor(mx, d2, 64));
      float sv = 0.f;
      sv += (v0 > -1e30f) ? fexp(v0 - mx) : 0.f;
      sv += (v1 > -1e30f) ? fexp(v1 - mx) : 0.f;
      sv += (v2 > -1e30f) ? fexp(v2 - mx) : 0.f;
      sv += (v3 > -1e30f) ? fexp(v3 - mx) : 0.f;
      #pragma unroll
      for (int d2 = 1; d2 < 16; d2 <<= 1) sv += __shfl_xor(sv, d2, 64);
      if (mok && l15 == 0)
        partials[(size_t)m * 784 + bn * 2 + wn] = make_float2(mx, sv);
    }
  }
}

// ---------------- row logsumexp reduce --------------------------------------
__global__ void reduce_rows(const float2* __restrict__ partials, float* __restrict__ lse) {
  int m = blockIdx.x, tid = threadIdx.x;
  float mx = -INFINITY, s = 0.f;
  for (int j = tid; j < 782; j += 256) {
    float2 p = partials[(size_t)m * 784 + j];
    if (p.x > mx) { s = s * fexp(mx - p.x) + p.y; mx = p.x; }
    else          { s += p.y * fexp(p.x - mx); }
  }
  for (int d = 1; d < 64; d <<= 1) {
    float omx = __shfl_xor(mx, d, 64);
    float os  = __shfl_xor(s, d, 64);
    if (omx > mx) { s = s * fexp(mx - omx) + os; mx = omx; }
    else          { s += os * fexp(omx - mx); }
  }
  __shared__ float smx[4], ssum[4];
  int w = tid >> 6;
  if ((tid & 63) == 0) { smx[w] = mx; ssum[w] = s; }
  __syncthreads();
  if (tid == 0) {
    for (int i = 1; i < 4; ++i) {
      float omx = smx[i], os = ssum[i];
      if (omx > mx) { s = s * fexp(mx - omx) + os; mx = omx; }
      else          { s += os * fexp(omx - mx); }
    }
    lse[m] = mx + logf(s);
  }
}

// ---------------- in-place log_softmax subtract -----------------------------
__global__ void sub_lse(float* __restrict__ out, const float* __restrict__ lse) {
  const int total4 = 14000000;  // 1120*50000/4
  for (int i = blockIdx.x * blockDim.x + threadIdx.x; i < total4; i += gridDim.x * blockDim.x) {
    int m = i / 12500;
    float4 v = ((float4*)out)[i];
    float L = lse[m];
    v.x -= L; v.y -= L; v.z -= L; v.w -= L;
    ((float4*)out)[i] = v;
  }
}

// ---------------- launch ----------------------------------------------------
extern "C" void kernel_launch(void* const* d_in, const int* in_sizes, int n_in,
                              void* d_out, int out_size, void* d_ws, size_t ws_size,
                              hipStream_t stream) {
  const int*   x_indices  = (const int*)d_in[0];
  const int*   edge_index = (const int*)d_in[1];
  const float* X          = (const float*)d_in[2];
  const float* gat_W      = (const float*)d_in[3];
  const float* att_src    = (const float*)d_in[4];
  const float* att_dst    = (const float*)d_in[5];
  const float* gat_bias   = (const float*)d_in[6];
  const float* W_ih0      = (const float*)d_in[7];
  const float* W_ih_rest  = (const float*)d_in[8];
  const float* W_hh       = (const float*)d_in[9];
  const float* b_ih       = (const float*)d_in[10];
  const float* b_hh       = (const float*)d_in[11];
  const float* lin_W      = (const float*)d_in[12];
  const float* lin_b      = (const float*)d_in[13];
  float* out = (float*)d_out;
  char* ws = (char*)d_ws;

  unsigned* flags    = (unsigned*)(ws + OFF_BAR);
  float*    ws_src   = (float*)(ws + OFF_WSRC);
  float*    ws_dst   = (float*)(ws + OFF_WDST);
  float*    bias_sum = (float*)(ws + OFF_BIAS);
  u16*      sig      = (u16*)(ws + OFF_SIG);
  u16*      wx0      = (u16*)(ws + OFF_WX0);
  u16*      wx12     = (u16*)(ws + OFF_WX12);
  float*    gates    = (float*)(ws + OFF_GATES);
  u16*      hist     = (u16*)(ws + OFF_HIST);
  float2*   partials = (float2*)(ws + OFF_PART);
  float*    lse      = (float*)(ws + OFF_LSE);
  u16*      linwb    = (u16*)(ws + OFF_LINWB);
  bool use_bw = (ws_size >= kNeedBW);

  u16* hist0 = hist;
  u16* hist1 = hist + (size_t)35 * 32 * 1024;
  u16* hist2 = hist + (size_t)2 * 35 * 32 * 1024;

  hipMemsetAsync(ws + OFF_BAR, 0, 1024, stream);
  prep_small<<<64, 256, 0, stream>>>(gat_W, att_src, att_dst, b_ih, b_hh,
                                     ws_src, ws_dst, bias_sum);
  wx_prep<<<1024, 256, 0, stream>>>(W_ih0, W_ih_rest, wx0, wx12);
  if (use_bw) wb_conv<<<2048, 256, 0, stream>>>(lin_W, linwb);
  gat_kernel<<<kG, 256, 0, stream>>>(x_indices, edge_index, X, gat_W, gat_bias,
                                     ws_src, ws_dst, sig);
  // layer 0
  gemm_ig<<<288, 256, 0, stream>>>(sig, wx0, gates, 640);
  lstm_rec<<<128, 256, 0, stream>>>(W_hh, gates, bias_sum, hist0, flags, 0u);
  // layer 1
  gemm_ig<<<288, 256, 0, stream>>>(hist0, wx12, gates, 1024);
  lstm_rec<<<128, 256, 0, stream>>>(W_hh + (size_t)4096 * 1024, gates,
                                    bias_sum + 4096, hist1, flags, 34u);
  // layer 2
  gemm_ig<<<288, 256, 0, stream>>>(hist1, wx12 + (size_t)4096 * 1024, gates, 1024);
  lstm_rec<<<128, 256, 0, stream>>>(W_hh + (size_t)2 * 4096 * 1024, gates,
                                    bias_sum + 8192, hist2, flags, 68u);
  // logits + log_softmax
  if (use_bw)
    gemm_logits<true><<<9 * 391, 256, 0, stream>>>(hist2, linwb, lin_W, lin_b, out, partials);
  else
    gemm_logits<false><<<9 * 391, 256, 0, stream>>>(hist2, nullptr, lin_W, lin_b, out, partials);
  reduce_rows<<<kG, 256, 0, stream>>>(partials, lse);
  sub_lse<<<2048, 256, 0, stream>>>(out, lse);
}